// Round 9
// baseline (866.368 us; speedup 1.0000x reference)
//
#include <hip/hip_runtime.h>
#include <hip/hip_bf16.h>

#define BATCH 2
#define SEQ   2048
#define DMODEL 2048
#define DINNER 4096
#define DXB   1024
#define NHEADS 64
#define NKV   16
#define HEADDIM 64
#define DSTATE 64
#define INTER 8192
#define DINPROJ 10304   // 4096 z + 1024 x + 1024 B + 4096 C + 64 dt
#define ROWS  (BATCH*SEQ)   // 4096
#define NC    32            // chunks per sequence
#define EPSV  1e-5f

typedef short short8 __attribute__((ext_vector_type(8)));
typedef float f32x4 __attribute__((ext_vector_type(4)));
typedef float f32x16 __attribute__((ext_vector_type(16)));

typedef const __attribute__((address_space(1))) unsigned int cg_u32;
typedef __attribute__((address_space(3))) unsigned int ls_u32;

static __device__ __forceinline__ void gll16(const void* g, void* l) {
    __builtin_amdgcn_global_load_lds((cg_u32*)g, (ls_u32*)l, 16, 0, 0);
}

static __device__ __forceinline__ unsigned short f2bf(float f) {
    unsigned int u = __float_as_uint(f);
    unsigned int r = (u + 0x7fffu + ((u >> 16) & 1u)) >> 16;
    return (unsigned short)r;
}
static __device__ __forceinline__ float bf2f(unsigned short h) {
    return __uint_as_float(((unsigned int)h) << 16);
}

// grid-stride f32->bf16 convert helper (fused into host kernels)
static __device__ __forceinline__ void conv_gs(const float* __restrict__ src,
                                               unsigned short* __restrict__ dst,
                                               int n4, int gtid, int gstride) {
    if (!src) return;
    for (int i = gtid; i < n4; i += gstride) {
        float4 v = ((const float4*)src)[i];
        ushort4 o;
        o.x = f2bf(v.x); o.y = f2bf(v.y); o.z = f2bf(v.z); o.w = f2bf(v.w);
        ((ushort4*)dst)[i] = o;
    }
}

// ---------------- LayerNorm (+ fused w_inp convert): one block per row ----------------
__global__ __launch_bounds__(256) void ln_kernel(const float* __restrict__ x,
                                                 const float* __restrict__ w,
                                                 const float* __restrict__ b,
                                                 unsigned short* __restrict__ hout,
                                                 const float* __restrict__ csrc,
                                                 unsigned short* __restrict__ cdst, int cn4) {
    int row = blockIdx.x;
    int t = threadIdx.x;
    const float* xr = x + (size_t)row * DMODEL;
    float v[8];
    float4 v0 = *(const float4*)&xr[t * 8];
    float4 v1 = *(const float4*)&xr[t * 8 + 4];
    v[0]=v0.x; v[1]=v0.y; v[2]=v0.z; v[3]=v0.w; v[4]=v1.x; v[5]=v1.y; v[6]=v1.z; v[7]=v1.w;
    float s = 0.f, s2 = 0.f;
    #pragma unroll
    for (int i = 0; i < 8; ++i) { s += v[i]; s2 += v[i]*v[i]; }
    #pragma unroll
    for (int off = 1; off < 64; off <<= 1) { s += __shfl_xor(s, off); s2 += __shfl_xor(s2, off); }
    __shared__ float sa[4], sb[4];
    int lane = t & 63, wv = t >> 6;
    if (lane == 0) { sa[wv] = s; sb[wv] = s2; }
    __syncthreads();
    s = sa[0]+sa[1]+sa[2]+sa[3];
    s2 = sb[0]+sb[1]+sb[2]+sb[3];
    float mu = s / DMODEL;
    float var = s2 / DMODEL - mu * mu;
    float sc = rsqrtf(var + EPSV);
    unsigned short* ho = hout + (size_t)row * DMODEL + t * 8;
    #pragma unroll
    for (int i = 0; i < 8; ++i) {
        int d = t * 8 + i;
        ho[i] = f2bf((v[i] - mu) * sc * w[d] + b[d]);
    }
    conv_gs(csrc, cdst, cn4, blockIdx.x * 256 + t, gridDim.x * 256);
}

// ---------------- pipelined bf16 MFMA GEMM: C[M,N] = A[M,K] * B[N,K]^T ----------
// R5 skeleton: 128x256 tile, BK=64, 8 waves (2x4), ring-3 LDS (144KB),
// global_load_lds staging with pre-swizzled source (T2), counted vmcnt(6) +
// 1 barrier per K-tile (T4), setprio (T5), by-fast XCD swizzle (T1).
// Compute: mfma_f32_32x32x16_bf16 (2x2 frags of 32x32 per wave).
// EPI 0: f32. EPI 1: gelu(acc+bias)->bf16. EPI 2: acc+bias+add1+add2->f32. EPI 3: bf16.
// Optional fused f32->bf16 weight conversion in epilogue (csrc/cdst/cn4).
#define SLOTSZ 49152
template <int EPI>
__global__ __launch_bounds__(512, 2) void gemm_p(
    const unsigned short* __restrict__ A, const unsigned short* __restrict__ B,
    int M, int N, int K, int nby,
    float* __restrict__ outF, unsigned short* __restrict__ outH,
    const float* __restrict__ bias, const float* __restrict__ add1,
    const float* __restrict__ add2,
    const float* __restrict__ csrc, unsigned short* __restrict__ cdst, int cn4) {
    __shared__ __align__(16) char smem[3 * SLOTSZ];
    int t = threadIdx.x, lane = t & 63, w = t >> 6;
    int nwg = gridDim.x, cpx = nwg >> 3;
    int logical = (blockIdx.x & 7) * cpx + (blockIdx.x >> 3);
    int by = logical % nby, bx = logical / nby;   // by-fast: B-tile reuse in L2
    int brow = by * 128, bcol = bx * 256;
    int wr = w >> 2, wc = w & 3;
    int wrb = wr * 64, wcb = wc * 64;

    // staging source (swizzled): lane l fetches row (l>>3), chunk (l&7)^(l>>3)
    int lr8 = lane >> 3;
    int lch = ((lane & 7) ^ lr8) << 3;          // element offset within 64-elem row
    const unsigned short* pa[2];
    #pragma unroll
    for (int j = 0; j < 2; ++j)
        pa[j] = A + (size_t)(brow + w * 16 + j * 8 + lr8) * K + lch;
    const unsigned short* pb[4];
    #pragma unroll
    for (int j = 0; j < 4; ++j) {
        int r = bcol + w * 32 + j * 8 + lr8;
        if (r > N - 1) r = N - 1;
        pb[j] = B + (size_t)r * K + lch;
    }
    auto stageA = [&](int slot, int j) {
        gll16(pa[j], smem + slot * SLOTSZ + (w * 16 + j * 8) * 128);
        pa[j] += 64;
    };
    auto stageB = [&](int slot, int j) {
        gll16(pb[j], smem + slot * SLOTSZ + 16384 + (w * 32 + j * 8) * 128);
        pb[j] += 64;
    };

    // fragment-read geometry (32x32x16): row = lane&31, k-half = lane>>5
    int arow = lane & 31;
    int khi = lane >> 5;

    f32x16 acc[2][2] = {};
    const int NT = K >> 6;
    #pragma unroll
    for (int j = 0; j < 2; ++j) stageA(0, j);
    #pragma unroll
    for (int j = 0; j < 4; ++j) stageB(0, j);
    #pragma unroll
    for (int j = 0; j < 2; ++j) stageA(1, j);
    #pragma unroll
    for (int j = 0; j < 4; ++j) stageB(1, j);

    int slot = 0, slot2 = 2;
    for (int kt = 0; kt < NT; ++kt) {
        if (kt + 1 < NT) { asm volatile("s_waitcnt vmcnt(6)" ::: "memory"); }
        else             { asm volatile("s_waitcnt vmcnt(0)" ::: "memory"); }
        __builtin_amdgcn_s_barrier();
        asm volatile("" ::: "memory");
        const char* Ab = smem + slot * SLOTSZ;
        const char* Bb = Ab + 16384;
        bool st = (kt + 2 < NT);
        short8 af[2][2], bfv[2][2];
        // ---- phase 0 (k-steps 0,1 of 4; k 0..31) ----
        #pragma unroll
        for (int ks = 0; ks < 2; ++ks) {
            int chunk = (ks << 1) | khi;
            #pragma unroll
            for (int f = 0; f < 2; ++f) {
                int r = wrb + f * 32 + arow;
                af[ks][f] = *(const short8*)(Ab + r * 128 + ((chunk ^ (r & 7)) << 4));
            }
            #pragma unroll
            for (int n = 0; n < 2; ++n) {
                int r = wcb + n * 32 + arow;
                bfv[ks][n] = *(const short8*)(Bb + r * 128 + ((chunk ^ (r & 7)) << 4));
            }
        }
        if (st) { stageA(slot2, 0); stageA(slot2, 1); stageB(slot2, 0); }
        __builtin_amdgcn_s_setprio(1);
        #pragma unroll
        for (int ks = 0; ks < 2; ++ks)
            #pragma unroll
            for (int f = 0; f < 2; ++f)
                #pragma unroll
                for (int n = 0; n < 2; ++n)
                    acc[f][n] = __builtin_amdgcn_mfma_f32_32x32x16_bf16(af[ks][f], bfv[ks][n], acc[f][n], 0, 0, 0);
        __builtin_amdgcn_s_setprio(0);
        // ---- phase 1 (k-steps 2,3; k 32..63) ----
        #pragma unroll
        for (int ks = 0; ks < 2; ++ks) {
            int chunk = ((ks + 2) << 1) | khi;
            #pragma unroll
            for (int f = 0; f < 2; ++f) {
                int r = wrb + f * 32 + arow;
                af[ks][f] = *(const short8*)(Ab + r * 128 + ((chunk ^ (r & 7)) << 4));
            }
            #pragma unroll
            for (int n = 0; n < 2; ++n) {
                int r = wcb + n * 32 + arow;
                bfv[ks][n] = *(const short8*)(Bb + r * 128 + ((chunk ^ (r & 7)) << 4));
            }
        }
        if (st) { stageB(slot2, 1); stageB(slot2, 2); stageB(slot2, 3); }
        __builtin_amdgcn_s_setprio(1);
        #pragma unroll
        for (int ks = 0; ks < 2; ++ks)
            #pragma unroll
            for (int f = 0; f < 2; ++f)
                #pragma unroll
                for (int n = 0; n < 2; ++n)
                    acc[f][n] = __builtin_amdgcn_mfma_f32_32x32x16_bf16(af[ks][f], bfv[ks][n], acc[f][n], 0, 0, 0);
        __builtin_amdgcn_s_setprio(0);
        slot  = (slot  == 2) ? 0 : slot + 1;
        slot2 = (slot2 == 2) ? 0 : slot2 + 1;
    }

    // epilogue: C/D layout col=lane&31, row=(reg&3)+8*(reg>>2)+4*(lane>>5)
    #pragma unroll
    for (int f = 0; f < 2; ++f) {
        #pragma unroll
        for (int n = 0; n < 2; ++n) {
            int col = bcol + wcb + n * 32 + arow;
            if (col < N) {
                #pragma unroll
                for (int reg = 0; reg < 16; ++reg) {
                    int row = brow + wrb + f * 32 + (reg & 3) + ((reg >> 2) << 3) + (khi << 2);
                    size_t idx = (size_t)row * N + col;
                    float v = acc[f][n][reg];
                    if constexpr (EPI == 0) {
                        outF[idx] = v;
                    } else if constexpr (EPI == 1) {
                        v += bias[col];
                        float g = 0.5f * v * (1.f + tanhf(0.7978845608f * (v + 0.044715f * v * v * v)));
                        outH[idx] = f2bf(g);
                    } else if constexpr (EPI == 2) {
                        outF[idx] = v + bias[col] + add1[idx] + add2[idx];
                    } else {
                        outH[idx] = f2bf(v);
                    }
                }
            }
        }
    }
    conv_gs(csrc, cdst, cn4, (int)blockIdx.x * 512 + t, nwg * 512);
}

// 64x64x64 bf16 MFMA: out rows = rows of Al, out cols = rows of Bl, K = inner 64.
static __device__ __forceinline__ void mm64(const unsigned short* Al, const unsigned short* Bl,
                                            f32x4* acc, int w, int lane) {
    int lr = lane & 15, kg = (lane >> 4) << 3;
    #pragma unroll
    for (int ks = 0; ks < 2; ++ks) {
        short8 a = *(const short8*)&Al[(w * 16 + lr) * 64 + ks * 32 + kg];
        #pragma unroll
        for (int fn = 0; fn < 4; ++fn) {
            short8 bb = *(const short8*)&Bl[(fn * 16 + lr) * 64 + ks * 32 + kg];
            acc[fn] = __builtin_amdgcn_mfma_f32_16x16x32_bf16(a, bb, acc[fn], 0, 0, 0);
        }
    }
}

// ---------------- K1: per-(b,h,chunk) intra-chunk work (dt fused, + w_fc1 convert) ----
__global__ __launch_bounds__(256) void chunk_front(const unsigned short* __restrict__ zx,
                                                   const float* __restrict__ dt_bias,
                                                   const float* __restrict__ A_log,
                                                   float* __restrict__ pcum,
                                                   unsigned short* __restrict__ ybuf,
                                                   unsigned short* __restrict__ Sbuf,
                                                   const float* __restrict__ csrc,
                                                   unsigned short* __restrict__ cdst, int cn4) {
    __shared__ __align__(16) unsigned short Cs[64*64], Bsr[64*64], Btr[64*64],
                                            Xtr[64*64], Xw[64*64], Wsm[64*64];
    __shared__ float dts[64], clg[64];
    int t = threadIdx.x, lane = t & 63, w = t >> 6;
    int bid = blockIdx.x;
    int c = bid & 31, h = (bid >> 5) & 63, b = bid >> 11, g = h >> 2;
    int row0 = (b << 11) + (c << 6);

    if (t < 64) {
        float raw = bf2f(zx[(size_t)(row0 + t) * DINPROJ + 10240 + h]) + dt_bias[h];
        float dt = raw > 20.f ? raw : log1pf(expf(raw));
        dts[t] = dt;
        float v = dt * (-expf(A_log[h]));
        #pragma unroll
        for (int off = 1; off < 64; off <<= 1) {
            float o = __shfl_up(v, off);
            if (lane >= off) v += o;
        }
        clg[t] = v;
        pcum[(size_t)(row0 + t) * 64 + h] = expf(v);
    }
    ushort4 xr[4];
    #pragma unroll
    for (int i = 0; i < 4; ++i) {
        int q = i * 256 + t, s = q >> 4, d4 = (q & 15) << 2;
        const unsigned short* rp = zx + (size_t)(row0 + s) * DINPROJ;
        ushort4 cv = *(const ushort4*)&rp[6144 + h * 64 + d4];
        *(ushort4*)&Cs[s * 64 + d4] = cv;
        ushort4 bv = *(const ushort4*)&rp[5120 + g * 64 + d4];
        *(ushort4*)&Bsr[s * 64 + d4] = bv;
        Btr[(d4 + 0) * 64 + s] = bv.x; Btr[(d4 + 1) * 64 + s] = bv.y;
        Btr[(d4 + 2) * 64 + s] = bv.z; Btr[(d4 + 3) * 64 + s] = bv.w;
        ushort4 xv = *(const ushort4*)&rp[4096 + g * 64 + d4];
        Xtr[(d4 + 0) * 64 + s] = xv.x; Xtr[(d4 + 1) * 64 + s] = xv.y;
        Xtr[(d4 + 2) * 64 + s] = xv.z; Xtr[(d4 + 3) * 64 + s] = xv.w;
        xr[i] = xv;
    }
    __syncthreads();
    float cl63 = clg[63];
    #pragma unroll
    for (int i = 0; i < 4; ++i) {
        int q = i * 256 + t, s = q >> 4, d4 = (q & 15) << 2;
        float ws = dts[s] * expf(cl63 - clg[s]);
        Xw[(d4 + 0) * 64 + s] = f2bf(bf2f(xr[i].x) * ws);
        Xw[(d4 + 1) * 64 + s] = f2bf(bf2f(xr[i].y) * ws);
        Xw[(d4 + 2) * 64 + s] = f2bf(bf2f(xr[i].z) * ws);
        Xw[(d4 + 3) * 64 + s] = f2bf(bf2f(xr[i].w) * ws);
    }
    __syncthreads();
    f32x4 accG[4] = {};
    mm64(Cs, Bsr, accG, w, lane);
    int rl = (lane >> 4) << 2, cl = lane & 15;
    #pragma unroll
    for (int fn = 0; fn < 4; ++fn) {
        #pragma unroll
        for (int j = 0; j < 4; ++j) {
            int tr = w * 16 + rl + j, rc = fn * 16 + cl;
            float val = 0.f;
            if (rc <= tr) val = accG[fn][j] * expf(clg[tr] - clg[rc]) * dts[rc];
            Wsm[tr * 64 + rc] = f2bf(val);
        }
    }
    __syncthreads();
    f32x4 accY[4] = {};
    mm64(Wsm, Xtr, accY, w, lane);
    f32x4 accS[4] = {};
    mm64(Xw, Btr, accS, w, lane);
    size_t cb = (size_t)((((b << 6) + h) << 5) + c) * 4096;
    #pragma unroll
    for (int fn = 0; fn < 4; ++fn) {
        #pragma unroll
        for (int j = 0; j < 4; ++j) {
            int tr = w * 16 + rl + j, pc = fn * 16 + cl;
            ybuf[(size_t)(row0 + tr) * DINNER + h * 64 + pc] = f2bf(accY[fn][j]);
            Sbuf[cb + tr * 64 + pc] = f2bf(accS[fn][j]);
        }
    }
    conv_gs(csrc, cdst, cn4, bid * 256 + t, (int)gridDim.x * 256);
}

// ---------------- K2: inter-chunk state recurrence (in-place S -> H0) ----------------
__global__ __launch_bounds__(256) void chunk_state(unsigned short* __restrict__ SH,
                                                   const float* __restrict__ pcum) {
    int b = blockIdx.x >> 6, h = blockIdx.x & 63, t = threadIdx.x;
    float H[16];
    #pragma unroll
    for (int j = 0; j < 16; ++j) H[j] = 0.f;
    for (int c = 0; c < NC; ++c) {
        size_t base = (size_t)((((b << 6) + h) << 5) + c) * 4096;
        float Tc = pcum[(size_t)((b << 11) + (c << 6) + 63) * 64 + h];
        #pragma unroll
        for (int j = 0; j < 16; ++j) {
            int e = j * 256 + t;
            unsigned short sv = SH[base + e];
            SH[base + e] = f2bf(H[j]);
            H[j] = H[j] * Tc + bf2f(sv);
        }
    }
}

// ---------------- K3: y += p_t * (C_t . H0) + Dp * x ----------------
__global__ __launch_bounds__(256) void chunk_back(const unsigned short* __restrict__ zx,
                                                  const unsigned short* __restrict__ SH,
                                                  const float* __restrict__ pcum,
                                                  const float* __restrict__ Dp,
                                                  unsigned short* __restrict__ ybuf) {
    __shared__ __align__(16) unsigned short Cs[64*64], Hs[64*64];
    __shared__ float ps[64];
    int t = threadIdx.x, lane = t & 63, w = t >> 6;
    int bid = blockIdx.x;
    int c = bid & 31, h = (bid >> 5) & 63, b = bid >> 11, g = h >> 2;
    int row0 = (b << 11) + (c << 6);
    size_t cb = (size_t)((((b << 6) + h) << 5) + c) * 4096;
    #pragma unroll
    for (int i = 0; i < 4; ++i) {
        int q = i * 256 + t, s = q >> 4, d4 = (q & 15) << 2;
        *(ushort4*)&Cs[s * 64 + d4] =
            *(const ushort4*)&zx[(size_t)(row0 + s) * DINPROJ + 6144 + h * 64 + d4];
        *(ushort4*)&Hs[s * 64 + d4] = *(const ushort4*)&SH[cb + s * 64 + d4];
    }
    if (t < 64) ps[t] = pcum[(size_t)(row0 + t) * 64 + h];
    __syncthreads();
    f32x4 acc[4] = {};
    mm64(Cs, Hs, acc, w, lane);
    float Dph = Dp[h];
    int rl = (lane >> 4) << 2, cl = lane & 15;
    #pragma unroll
    for (int fn = 0; fn < 4; ++fn) {
        #pragma unroll
        for (int j = 0; j < 4; ++j) {
            int tr = w * 16 + rl + j, pc = fn * 16 + cl;
            size_t yi = (size_t)(row0 + tr) * DINNER + h * 64 + pc;
            float xv = bf2f(zx[(size_t)(row0 + tr) * DINPROJ + 4096 + g * 64 + pc]);
            ybuf[yi] = f2bf(bf2f(ybuf[yi]) + acc[fn][j] * ps[tr] + Dph * xv);
        }
    }
}

// ---------------- gate (silu) + RMSNorm -> bf16 yf ----------------
__global__ __launch_bounds__(256) void gate_kernel(const unsigned short* __restrict__ y,
                                                   const unsigned short* __restrict__ zx,
                                                   const float* __restrict__ norm_w,
                                                   unsigned short* __restrict__ yf) {
    int row = blockIdx.x;
    int t = threadIdx.x;
    float v[16];
    float s2 = 0.f;
    #pragma unroll
    for (int i = 0; i < 16; ++i) {
        int d = i * 256 + t;
        float yv = bf2f(y[(size_t)row * DINNER + d]);
        float zv = bf2f(zx[(size_t)row * DINPROJ + d]);
        float gt = zv / (1.f + expf(-zv));
        v[i] = yv * gt;
        s2 += v[i] * v[i];
    }
    #pragma unroll
    for (int off = 1; off < 64; off <<= 1) s2 += __shfl_xor(s2, off);
    __shared__ float sb[4];
    int lane = t & 63, wv = t >> 6;
    if (lane == 0) sb[wv] = s2;
    __syncthreads();
    s2 = sb[0] + sb[1] + sb[2] + sb[3];
    float sc = rsqrtf(s2 / DINNER + EPSV);
    #pragma unroll
    for (int i = 0; i < 16; ++i) {
        int d = i * 256 + t;
        yf[(size_t)row * DINNER + d] = f2bf(v[i] * sc * norm_w[d]);
    }
}

extern "C" void kernel_launch(void* const* d_in, const int* in_sizes, int n_in,
                              void* d_out, int out_size, void* d_ws, size_t ws_size,
                              hipStream_t stream) {
    const float* hid   = (const float*)d_in[0];
    const float* ln_w  = (const float*)d_in[1];
    const float* ln_b  = (const float*)d_in[2];
    const float* w_inp = (const float*)d_in[3];
    const float* dtb   = (const float*)d_in[4];
    const float* A_log = (const float*)d_in[5];
    const float* Dp    = (const float*)d_in[6];
    const float* nw    = (const float*)d_in[7];
    const float* w_out = (const float*)d_in[8];
    const float* w_fc1 = (const float*)d_in[9];
    const float* fc1_b = (const float*)d_in[10];
    const float* w_fc2 = (const float*)d_in[11];
    const float* fc2_b = (const float*)d_in[12];

    char* ws = (char*)d_ws;
    size_t off = 0;
    auto alloc = [&](size_t bytes) { size_t o = off; off += (bytes + 255) & ~(size_t)255; return o; };
    size_t o_h    = alloc((size_t)ROWS * DMODEL * 2);        // h bf16
    size_t o_wi   = alloc((size_t)DINPROJ * DMODEL * 2);     // w_inp bf16
    size_t o_wo   = alloc((size_t)DMODEL * DINNER * 2);      // w_out bf16
    size_t o_wf1  = alloc((size_t)INTER * DMODEL * 2);       // w_fc1 bf16
    size_t o_wf2  = alloc((size_t)DMODEL * INTER * 2);       // w_fc2 bf16
    size_t o_zx   = alloc((size_t)ROWS * DINPROJ * 2);       // zxbcdt bf16 (later: gelu bf16)
    size_t o_pc   = alloc((size_t)ROWS * NHEADS * 4);        // pcum f32
    size_t o_y    = alloc((size_t)ROWS * DINNER * 2);        // y bf16 (later: mamba f32 area reuse)
    size_t o_yf   = alloc((size_t)ROWS * DINNER * 2);        // yf bf16
    size_t o_S    = alloc((size_t)BATCH * NHEADS * NC * HEADDIM * DSTATE * 2); // S->H0 bf16

    unsigned short* h_bf  = (unsigned short*)(ws + o_h);
    unsigned short* wbi   = (unsigned short*)(ws + o_wi);
    unsigned short* wbo   = (unsigned short*)(ws + o_wo);
    unsigned short* wbf1  = (unsigned short*)(ws + o_wf1);
    unsigned short* wbf2  = (unsigned short*)(ws + o_wf2);
    unsigned short* zx    = (unsigned short*)(ws + o_zx);
    float* pcum           = (float*)(ws + o_pc);
    unsigned short* ybuf  = (unsigned short*)(ws + o_y);
    unsigned short* yf    = (unsigned short*)(ws + o_yf);
    unsigned short* Sbuf  = (unsigned short*)(ws + o_S);
    unsigned short* gelu  = (unsigned short*)(ws + o_zx);    // alias: zx dead after gate
    float* mamba          = (float*)(ws + o_y);              // alias: y dead after gate
    float* outF           = (float*)d_out;

    // 1) LayerNorm -> h (bf16); fused convert w_inp -> wbi
    ln_kernel<<<ROWS, 256, 0, stream>>>(hid, ln_w, ln_b, h_bf,
                                        w_inp, wbi, (DINPROJ * DMODEL) / 4);
    // 2) in_proj GEMM -> zx (bf16); fused convert w_out -> wbo
    gemm_p<3><<<41 * 32, 512, 0, stream>>>(
        h_bf, wbi, ROWS, DINPROJ, DMODEL, 32, nullptr, zx, nullptr, nullptr, nullptr,
        w_out, wbo, (DMODEL * DINNER) / 4);
    // 3) chunked SSD scan (dt softplus fused into chunk_front; convert w_fc1 -> wbf1)
    chunk_front<<<BATCH * NHEADS * NC, 256, 0, stream>>>(zx, dtb, A_log, pcum, ybuf, Sbuf,
                                                         w_fc1, wbf1, (INTER * DMODEL) / 4);
    chunk_state<<<BATCH * NHEADS, 256, 0, stream>>>(Sbuf, pcum);
    chunk_back<<<BATCH * NHEADS * NC, 256, 0, stream>>>(zx, Sbuf, pcum, Dp, ybuf);
    // 4) gate + RMSNorm -> yf (bf16)
    gate_kernel<<<ROWS, 256, 0, stream>>>(ybuf, zx, nw, yf);
    // 5) out_proj GEMM -> mamba (f32); fused convert w_fc2 -> wbf2
    gemm_p<0><<<8 * 32, 512, 0, stream>>>(
        yf, wbo, ROWS, DMODEL, DINNER, 32, mamba, nullptr, nullptr, nullptr, nullptr,
        w_fc2, wbf2, (DMODEL * INTER) / 4);
    // 6) fc1 GEMM + gelu -> gelu (bf16, aliases zx)
    gemm_p<1><<<32 * 32, 512, 0, stream>>>(
        h_bf, wbf1, ROWS, INTER, DMODEL, 32, nullptr, gelu, fc1_b, nullptr, nullptr,
        nullptr, nullptr, 0);
    // 7) fc2 GEMM + bias + mamba + residual -> d_out (f32)
    gemm_p<2><<<8 * 32, 512, 0, stream>>>(
        gelu, wbf2, ROWS, DMODEL, INTER, 32, outF, nullptr, fc2_b, mamba, hid,
        nullptr, nullptr, 0);
}

// Round 10
// 823.236 us; speedup vs baseline: 1.0524x; 1.0524x over previous
//
#include <hip/hip_runtime.h>
#include <hip/hip_bf16.h>

#define BATCH 2
#define SEQ   2048
#define DMODEL 2048
#define DINNER 4096
#define DXB   1024
#define NHEADS 64
#define NKV   16
#define HEADDIM 64
#define DSTATE 64
#define INTER 8192
#define DINPROJ 10304   // 4096 z + 1024 x + 1024 B + 4096 C + 64 dt
#define ROWS  (BATCH*SEQ)   // 4096
#define NC    32            // chunks per sequence
#define EPSV  1e-5f

typedef short short8 __attribute__((ext_vector_type(8)));
typedef float f32x4 __attribute__((ext_vector_type(4)));

typedef const __attribute__((address_space(1))) unsigned int cg_u32;
typedef __attribute__((address_space(3))) unsigned int ls_u32;

static __device__ __forceinline__ void gll16(const void* g, void* l) {
    __builtin_amdgcn_global_load_lds((cg_u32*)g, (ls_u32*)l, 16, 0, 0);
}

static __device__ __forceinline__ unsigned short f2bf(float f) {
    unsigned int u = __float_as_uint(f);
    unsigned int r = (u + 0x7fffu + ((u >> 16) & 1u)) >> 16;
    return (unsigned short)r;
}
static __device__ __forceinline__ float bf2f(unsigned short h) {
    return __uint_as_float(((unsigned int)h) << 16);
}

// grid-stride f32->bf16 convert helper (fused into host kernels)
static __device__ __forceinline__ void conv_gs(const float* __restrict__ src,
                                               unsigned short* __restrict__ dst,
                                               int n4, int gtid, int gstride) {
    if (!src) return;
    for (int i = gtid; i < n4; i += gstride) {
        float4 v = ((const float4*)src)[i];
        ushort4 o;
        o.x = f2bf(v.x); o.y = f2bf(v.y); o.z = f2bf(v.z); o.w = f2bf(v.w);
        ((ushort4*)dst)[i] = o;
    }
}

// ---------------- LayerNorm (+ fused w_inp convert): one block per row ----------------
__global__ __launch_bounds__(256) void ln_kernel(const float* __restrict__ x,
                                                 const float* __restrict__ w,
                                                 const float* __restrict__ b,
                                                 unsigned short* __restrict__ hout,
                                                 const float* __restrict__ csrc,
                                                 unsigned short* __restrict__ cdst, int cn4) {
    int row = blockIdx.x;
    int t = threadIdx.x;
    const float* xr = x + (size_t)row * DMODEL;
    float v[8];
    float4 v0 = *(const float4*)&xr[t * 8];
    float4 v1 = *(const float4*)&xr[t * 8 + 4];
    v[0]=v0.x; v[1]=v0.y; v[2]=v0.z; v[3]=v0.w; v[4]=v1.x; v[5]=v1.y; v[6]=v1.z; v[7]=v1.w;
    float s = 0.f, s2 = 0.f;
    #pragma unroll
    for (int i = 0; i < 8; ++i) { s += v[i]; s2 += v[i]*v[i]; }
    #pragma unroll
    for (int off = 1; off < 64; off <<= 1) { s += __shfl_xor(s, off); s2 += __shfl_xor(s2, off); }
    __shared__ float sa[4], sb[4];
    int lane = t & 63, wv = t >> 6;
    if (lane == 0) { sa[wv] = s; sb[wv] = s2; }
    __syncthreads();
    s = sa[0]+sa[1]+sa[2]+sa[3];
    s2 = sb[0]+sb[1]+sb[2]+sb[3];
    float mu = s / DMODEL;
    float var = s2 / DMODEL - mu * mu;
    float sc = rsqrtf(var + EPSV);
    unsigned short* ho = hout + (size_t)row * DMODEL + t * 8;
    #pragma unroll
    for (int i = 0; i < 8; ++i) {
        int d = t * 8 + i;
        ho[i] = f2bf((v[i] - mu) * sc * w[d] + b[d]);
    }
    conv_gs(csrc, cdst, cn4, blockIdx.x * 256 + t, gridDim.x * 256);
}

// ---------------- pipelined bf16 MFMA GEMM: C[M,N] = A[M,K] * B[N,K]^T ----------
// R5/R8 skeleton (best-known): 128x256 tile, BK=64, 8 waves (2x4), ring-3 LDS
// (144KB), global_load_lds staging with pre-swizzled source (T2), counted
// vmcnt(6) + 1 barrier per K-tile (T4), setprio (T5), by-fast XCD swizzle (T1).
// Compute: mfma_f32_16x16x32_bf16 (4x4 frags, verified 0 LDS conflicts).
// EPI 0: f32. EPI 1: gelu(acc+bias)->bf16. EPI 2: acc+bias+add1+add2->f32. EPI 3: bf16.
// Optional fused f32->bf16 weight conversion after epilogue (csrc/cdst/cn4).
#define SLOTSZ 49152
template <int EPI>
__global__ __launch_bounds__(512, 2) void gemm_p(
    const unsigned short* __restrict__ A, const unsigned short* __restrict__ B,
    int M, int N, int K, int nby,
    float* __restrict__ outF, unsigned short* __restrict__ outH,
    const float* __restrict__ bias, const float* __restrict__ add1,
    const float* __restrict__ add2,
    const float* __restrict__ csrc, unsigned short* __restrict__ cdst, int cn4) {
    __shared__ __align__(16) char smem[3 * SLOTSZ];
    int t = threadIdx.x, lane = t & 63, w = t >> 6;
    int nwg = gridDim.x, cpx = nwg >> 3;
    int logical = (blockIdx.x & 7) * cpx + (blockIdx.x >> 3);
    int by = logical % nby, bx = logical / nby;   // by-fast: B-tile reuse in L2
    int brow = by * 128, bcol = bx * 256;
    int wr = w >> 2, wc = w & 3;
    int wrb = wr * 64, wcb = wc * 64;

    // staging source (swizzled): lane l fetches row (l>>3), chunk (l&7)^(l>>3)
    int lr8 = lane >> 3;
    int lch = ((lane & 7) ^ lr8) << 3;          // element offset within 64-elem row
    const unsigned short* pa[2];
    #pragma unroll
    for (int j = 0; j < 2; ++j)
        pa[j] = A + (size_t)(brow + w * 16 + j * 8 + lr8) * K + lch;
    const unsigned short* pb[4];
    #pragma unroll
    for (int j = 0; j < 4; ++j) {
        int r = bcol + w * 32 + j * 8 + lr8;
        if (r > N - 1) r = N - 1;
        pb[j] = B + (size_t)r * K + lch;
    }
    auto stageA = [&](int slot, int j) {
        gll16(pa[j], smem + slot * SLOTSZ + (w * 16 + j * 8) * 128);
        pa[j] += 64;
    };
    auto stageB = [&](int slot, int j) {
        gll16(pb[j], smem + slot * SLOTSZ + 16384 + (w * 32 + j * 8) * 128);
        pb[j] += 64;
    };

    // fragment-read swizzle: byte = row*128 + ((c ^ (row&7))*16), c = ks*4 + (lane>>4)
    int arow = lane & 15;
    int swz0 = (((lane >> 4) ^ (lane & 7)) << 4);

    f32x4 acc[4][4] = {};
    const int NT = K >> 6;
    #pragma unroll
    for (int j = 0; j < 2; ++j) stageA(0, j);
    #pragma unroll
    for (int j = 0; j < 4; ++j) stageB(0, j);
    #pragma unroll
    for (int j = 0; j < 2; ++j) stageA(1, j);
    #pragma unroll
    for (int j = 0; j < 4; ++j) stageB(1, j);

    int slot = 0, slot2 = 2;
    for (int kt = 0; kt < NT; ++kt) {
        if (kt + 1 < NT) { asm volatile("s_waitcnt vmcnt(6)" ::: "memory"); }
        else             { asm volatile("s_waitcnt vmcnt(0)" ::: "memory"); }
        __builtin_amdgcn_s_barrier();
        asm volatile("" ::: "memory");
        const char* Ab = smem + slot * SLOTSZ;
        const char* Bb = Ab + 16384;
        bool st = (kt + 2 < NT);
        // ---- phase 0 (k 0..31) ----
        short8 af[4], bfv[4];
        #pragma unroll
        for (int f = 0; f < 4; ++f)
            af[f] = *(const short8*)(Ab + (wrb + f * 16 + arow) * 128 + swz0);
        #pragma unroll
        for (int n = 0; n < 4; ++n)
            bfv[n] = *(const short8*)(Bb + (wcb + n * 16 + arow) * 128 + swz0);
        if (st) { stageA(slot2, 0); stageA(slot2, 1); stageB(slot2, 0); }
        __builtin_amdgcn_s_setprio(1);
        #pragma unroll
        for (int f = 0; f < 4; ++f)
            #pragma unroll
            for (int n = 0; n < 4; ++n)
                acc[f][n] = __builtin_amdgcn_mfma_f32_16x16x32_bf16(af[f], bfv[n], acc[f][n], 0, 0, 0);
        __builtin_amdgcn_s_setprio(0);
        // ---- phase 1 (k 32..63) ----
        #pragma unroll
        for (int f = 0; f < 4; ++f)
            af[f] = *(const short8*)(Ab + (wrb + f * 16 + arow) * 128 + (swz0 ^ 64));
        #pragma unroll
        for (int n = 0; n < 4; ++n)
            bfv[n] = *(const short8*)(Bb + (wcb + n * 16 + arow) * 128 + (swz0 ^ 64));
        if (st) { stageB(slot2, 1); stageB(slot2, 2); stageB(slot2, 3); }
        __builtin_amdgcn_s_setprio(1);
        #pragma unroll
        for (int f = 0; f < 4; ++f)
            #pragma unroll
            for (int n = 0; n < 4; ++n)
                acc[f][n] = __builtin_amdgcn_mfma_f32_16x16x32_bf16(af[f], bfv[n], acc[f][n], 0, 0, 0);
        __builtin_amdgcn_s_setprio(0);
        slot  = (slot  == 2) ? 0 : slot + 1;
        slot2 = (slot2 == 2) ? 0 : slot2 + 1;
    }

    int rlane = (lane >> 4) << 2, clane = lane & 15;
    #pragma unroll
    for (int f = 0; f < 4; ++f) {
        #pragma unroll
        for (int n = 0; n < 4; ++n) {
            int col = bcol + wcb + n * 16 + clane;
            if (col < N) {
                #pragma unroll
                for (int j = 0; j < 4; ++j) {
                    int row = brow + wrb + f * 16 + rlane + j;
                    size_t idx = (size_t)row * N + col;
                    float v = acc[f][n][j];
                    if constexpr (EPI == 0) {
                        outF[idx] = v;
                    } else if constexpr (EPI == 1) {
                        v += bias[col];
                        float g = 0.5f * v * (1.f + tanhf(0.7978845608f * (v + 0.044715f * v * v * v)));
                        outH[idx] = f2bf(g);
                    } else if constexpr (EPI == 2) {
                        outF[idx] = v + bias[col] + add1[idx] + add2[idx];
                    } else {
                        outH[idx] = f2bf(v);
                    }
                }
            }
        }
    }
    conv_gs(csrc, cdst, cn4, (int)blockIdx.x * 512 + t, nwg * 512);
}

// 64x64x64 bf16 MFMA: out rows = rows of Al, out cols = rows of Bl, K = inner 64.
static __device__ __forceinline__ void mm64(const unsigned short* Al, const unsigned short* Bl,
                                            f32x4* acc, int w, int lane) {
    int lr = lane & 15, kg = (lane >> 4) << 3;
    #pragma unroll
    for (int ks = 0; ks < 2; ++ks) {
        short8 a = *(const short8*)&Al[(w * 16 + lr) * 64 + ks * 32 + kg];
        #pragma unroll
        for (int fn = 0; fn < 4; ++fn) {
            short8 bb = *(const short8*)&Bl[(fn * 16 + lr) * 64 + ks * 32 + kg];
            acc[fn] = __builtin_amdgcn_mfma_f32_16x16x32_bf16(a, bb, acc[fn], 0, 0, 0);
        }
    }
}

// ---------------- K1: per-(b,h,chunk) intra-chunk work (dt fused, + w_fc1 convert) ----
__global__ __launch_bounds__(256) void chunk_front(const unsigned short* __restrict__ zx,
                                                   const float* __restrict__ dt_bias,
                                                   const float* __restrict__ A_log,
                                                   float* __restrict__ pcum,
                                                   unsigned short* __restrict__ ybuf,
                                                   unsigned short* __restrict__ Sbuf,
                                                   const float* __restrict__ csrc,
                                                   unsigned short* __restrict__ cdst, int cn4) {
    __shared__ __align__(16) unsigned short Cs[64*64], Bsr[64*64], Btr[64*64],
                                            Xtr[64*64], Xw[64*64], Wsm[64*64];
    __shared__ float dts[64], clg[64];
    int t = threadIdx.x, lane = t & 63, w = t >> 6;
    int bid = blockIdx.x;
    int c = bid & 31, h = (bid >> 5) & 63, b = bid >> 11, g = h >> 2;
    int row0 = (b << 11) + (c << 6);

    if (t < 64) {
        float raw = bf2f(zx[(size_t)(row0 + t) * DINPROJ + 10240 + h]) + dt_bias[h];
        float dt = raw > 20.f ? raw : log1pf(expf(raw));
        dts[t] = dt;
        float v = dt * (-expf(A_log[h]));
        #pragma unroll
        for (int off = 1; off < 64; off <<= 1) {
            float o = __shfl_up(v, off);
            if (lane >= off) v += o;
        }
        clg[t] = v;
        pcum[(size_t)(row0 + t) * 64 + h] = expf(v);
    }
    ushort4 xr[4];
    #pragma unroll
    for (int i = 0; i < 4; ++i) {
        int q = i * 256 + t, s = q >> 4, d4 = (q & 15) << 2;
        const unsigned short* rp = zx + (size_t)(row0 + s) * DINPROJ;
        ushort4 cv = *(const ushort4*)&rp[6144 + h * 64 + d4];
        *(ushort4*)&Cs[s * 64 + d4] = cv;
        ushort4 bv = *(const ushort4*)&rp[5120 + g * 64 + d4];
        *(ushort4*)&Bsr[s * 64 + d4] = bv;
        Btr[(d4 + 0) * 64 + s] = bv.x; Btr[(d4 + 1) * 64 + s] = bv.y;
        Btr[(d4 + 2) * 64 + s] = bv.z; Btr[(d4 + 3) * 64 + s] = bv.w;
        ushort4 xv = *(const ushort4*)&rp[4096 + g * 64 + d4];
        Xtr[(d4 + 0) * 64 + s] = xv.x; Xtr[(d4 + 1) * 64 + s] = xv.y;
        Xtr[(d4 + 2) * 64 + s] = xv.z; Xtr[(d4 + 3) * 64 + s] = xv.w;
        xr[i] = xv;
    }
    __syncthreads();
    float cl63 = clg[63];
    #pragma unroll
    for (int i = 0; i < 4; ++i) {
        int q = i * 256 + t, s = q >> 4, d4 = (q & 15) << 2;
        float ws = dts[s] * expf(cl63 - clg[s]);
        Xw[(d4 + 0) * 64 + s] = f2bf(bf2f(xr[i].x) * ws);
        Xw[(d4 + 1) * 64 + s] = f2bf(bf2f(xr[i].y) * ws);
        Xw[(d4 + 2) * 64 + s] = f2bf(bf2f(xr[i].z) * ws);
        Xw[(d4 + 3) * 64 + s] = f2bf(bf2f(xr[i].w) * ws);
    }
    __syncthreads();
    f32x4 accG[4] = {};
    mm64(Cs, Bsr, accG, w, lane);
    int rl = (lane >> 4) << 2, cl = lane & 15;
    #pragma unroll
    for (int fn = 0; fn < 4; ++fn) {
        #pragma unroll
        for (int j = 0; j < 4; ++j) {
            int tr = w * 16 + rl + j, rc = fn * 16 + cl;
            float val = 0.f;
            if (rc <= tr) val = accG[fn][j] * expf(clg[tr] - clg[rc]) * dts[rc];
            Wsm[tr * 64 + rc] = f2bf(val);
        }
    }
    __syncthreads();
    f32x4 accY[4] = {};
    mm64(Wsm, Xtr, accY, w, lane);
    f32x4 accS[4] = {};
    mm64(Xw, Btr, accS, w, lane);
    size_t cb = (size_t)((((b << 6) + h) << 5) + c) * 4096;
    #pragma unroll
    for (int fn = 0; fn < 4; ++fn) {
        #pragma unroll
        for (int j = 0; j < 4; ++j) {
            int tr = w * 16 + rl + j, pc = fn * 16 + cl;
            ybuf[(size_t)(row0 + tr) * DINNER + h * 64 + pc] = f2bf(accY[fn][j]);
            Sbuf[cb + tr * 64 + pc] = f2bf(accS[fn][j]);
        }
    }
    conv_gs(csrc, cdst, cn4, bid * 256 + t, (int)gridDim.x * 256);
}

// ---------------- K2: inter-chunk state recurrence (in-place S -> H0) ----------------
__global__ __launch_bounds__(256) void chunk_state(unsigned short* __restrict__ SH,
                                                   const float* __restrict__ pcum) {
    int b = blockIdx.x >> 6, h = blockIdx.x & 63, t = threadIdx.x;
    float H[16];
    #pragma unroll
    for (int j = 0; j < 16; ++j) H[j] = 0.f;
    for (int c = 0; c < NC; ++c) {
        size_t base = (size_t)((((b << 6) + h) << 5) + c) * 4096;
        float Tc = pcum[(size_t)((b << 11) + (c << 6) + 63) * 64 + h];
        #pragma unroll
        for (int j = 0; j < 16; ++j) {
            int e = j * 256 + t;
            unsigned short sv = SH[base + e];
            SH[base + e] = f2bf(H[j]);
            H[j] = H[j] * Tc + bf2f(sv);
        }
    }
}

// ---------------- K3: y += p_t * (C_t . H0) + Dp * x ----------------
__global__ __launch_bounds__(256) void chunk_back(const unsigned short* __restrict__ zx,
                                                  const unsigned short* __restrict__ SH,
                                                  const float* __restrict__ pcum,
                                                  const float* __restrict__ Dp,
                                                  unsigned short* __restrict__ ybuf) {
    __shared__ __align__(16) unsigned short Cs[64*64], Hs[64*64];
    __shared__ float ps[64];
    int t = threadIdx.x, lane = t & 63, w = t >> 6;
    int bid = blockIdx.x;
    int c = bid & 31, h = (bid >> 5) & 63, b = bid >> 11, g = h >> 2;
    int row0 = (b << 11) + (c << 6);
    size_t cb = (size_t)((((b << 6) + h) << 5) + c) * 4096;
    #pragma unroll
    for (int i = 0; i < 4; ++i) {
        int q = i * 256 + t, s = q >> 4, d4 = (q & 15) << 2;
        *(ushort4*)&Cs[s * 64 + d4] =
            *(const ushort4*)&zx[(size_t)(row0 + s) * DINPROJ + 6144 + h * 64 + d4];
        *(ushort4*)&Hs[s * 64 + d4] = *(const ushort4*)&SH[cb + s * 64 + d4];
    }
    if (t < 64) ps[t] = pcum[(size_t)(row0 + t) * 64 + h];
    __syncthreads();
    f32x4 acc[4] = {};
    mm64(Cs, Hs, acc, w, lane);
    float Dph = Dp[h];
    int rl = (lane >> 4) << 2, cl = lane & 15;
    #pragma unroll
    for (int fn = 0; fn < 4; ++fn) {
        #pragma unroll
        for (int j = 0; j < 4; ++j) {
            int tr = w * 16 + rl + j, pc = fn * 16 + cl;
            size_t yi = (size_t)(row0 + tr) * DINNER + h * 64 + pc;
            float xv = bf2f(zx[(size_t)(row0 + tr) * DINPROJ + 4096 + g * 64 + pc]);
            ybuf[yi] = f2bf(bf2f(ybuf[yi]) + acc[fn][j] * ps[tr] + Dph * xv);
        }
    }
}

// ---------------- gate (silu) + RMSNorm -> bf16 yf ----------------
__global__ __launch_bounds__(256) void gate_kernel(const unsigned short* __restrict__ y,
                                                   const unsigned short* __restrict__ zx,
                                                   const float* __restrict__ norm_w,
                                                   unsigned short* __restrict__ yf) {
    int row = blockIdx.x;
    int t = threadIdx.x;
    float v[16];
    float s2 = 0.f;
    #pragma unroll
    for (int i = 0; i < 16; ++i) {
        int d = i * 256 + t;
        float yv = bf2f(y[(size_t)row * DINNER + d]);
        float zv = bf2f(zx[(size_t)row * DINPROJ + d]);
        float gt = zv / (1.f + expf(-zv));
        v[i] = yv * gt;
        s2 += v[i] * v[i];
    }
    #pragma unroll
    for (int off = 1; off < 64; off <<= 1) s2 += __shfl_xor(s2, off);
    __shared__ float sb[4];
    int lane = t & 63, wv = t >> 6;
    if (lane == 0) sb[wv] = s2;
    __syncthreads();
    s2 = sb[0] + sb[1] + sb[2] + sb[3];
    float sc = rsqrtf(s2 / DINNER + EPSV);
    #pragma unroll
    for (int i = 0; i < 16; ++i) {
        int d = i * 256 + t;
        yf[(size_t)row * DINNER + d] = f2bf(v[i] * sc * norm_w[d]);
    }
}

extern "C" void kernel_launch(void* const* d_in, const int* in_sizes, int n_in,
                              void* d_out, int out_size, void* d_ws, size_t ws_size,
                              hipStream_t stream) {
    const float* hid   = (const float*)d_in[0];
    const float* ln_w  = (const float*)d_in[1];
    const float* ln_b  = (const float*)d_in[2];
    const float* w_inp = (const float*)d_in[3];
    const float* dtb   = (const float*)d_in[4];
    const float* A_log = (const float*)d_in[5];
    const float* Dp    = (const float*)d_in[6];
    const float* nw    = (const float*)d_in[7];
    const float* w_out = (const float*)d_in[8];
    const float* w_fc1 = (const float*)d_in[9];
    const float* fc1_b = (const float*)d_in[10];
    const float* w_fc2 = (const float*)d_in[11];
    const float* fc2_b = (const float*)d_in[12];

    char* ws = (char*)d_ws;
    size_t off = 0;
    auto alloc = [&](size_t bytes) { size_t o = off; off += (bytes + 255) & ~(size_t)255; return o; };
    size_t o_h    = alloc((size_t)ROWS * DMODEL * 2);        // h bf16
    size_t o_wi   = alloc((size_t)DINPROJ * DMODEL * 2);     // w_inp bf16
    size_t o_wo   = alloc((size_t)DMODEL * DINNER * 2);      // w_out bf16
    size_t o_wf1  = alloc((size_t)INTER * DMODEL * 2);       // w_fc1 bf16
    size_t o_wf2  = alloc((size_t)DMODEL * INTER * 2);       // w_fc2 bf16
    size_t o_zx   = alloc((size_t)ROWS * DINPROJ * 2);       // zxbcdt bf16 (later: gelu bf16)
    size_t o_pc   = alloc((size_t)ROWS * NHEADS * 4);        // pcum f32
    size_t o_y    = alloc((size_t)ROWS * DINNER * 2);        // y bf16 (later: mamba f32 area reuse)
    size_t o_yf   = alloc((size_t)ROWS * DINNER * 2);        // yf bf16
    size_t o_S    = alloc((size_t)BATCH * NHEADS * NC * HEADDIM * DSTATE * 2); // S->H0 bf16

    unsigned short* h_bf  = (unsigned short*)(ws + o_h);
    unsigned short* wbi   = (unsigned short*)(ws + o_wi);
    unsigned short* wbo   = (unsigned short*)(ws + o_wo);
    unsigned short* wbf1  = (unsigned short*)(ws + o_wf1);
    unsigned short* wbf2  = (unsigned short*)(ws + o_wf2);
    unsigned short* zx    = (unsigned short*)(ws + o_zx);
    float* pcum           = (float*)(ws + o_pc);
    unsigned short* ybuf  = (unsigned short*)(ws + o_y);
    unsigned short* yf    = (unsigned short*)(ws + o_yf);
    unsigned short* Sbuf  = (unsigned short*)(ws + o_S);
    unsigned short* gelu  = (unsigned short*)(ws + o_zx);    // alias: zx dead after gate
    float* mamba          = (float*)(ws + o_y);              // alias: y dead after gate
    float* outF           = (float*)d_out;

    // 1) LayerNorm -> h (bf16); fused convert w_inp -> wbi
    ln_kernel<<<ROWS, 256, 0, stream>>>(hid, ln_w, ln_b, h_bf,
                                        w_inp, wbi, (DINPROJ * DMODEL) / 4);
    // 2) in_proj GEMM -> zx (bf16); fused convert w_out -> wbo
    gemm_p<3><<<41 * 32, 512, 0, stream>>>(
        h_bf, wbi, ROWS, DINPROJ, DMODEL, 32, nullptr, zx, nullptr, nullptr, nullptr,
        w_out, wbo, (DMODEL * DINNER) / 4);
    // 3) chunked SSD scan (dt softplus fused into chunk_front; convert w_fc1 -> wbf1)
    chunk_front<<<BATCH * NHEADS * NC, 256, 0, stream>>>(zx, dtb, A_log, pcum, ybuf, Sbuf,
                                                         w_fc1, wbf1, (INTER * DMODEL) / 4);
    chunk_state<<<BATCH * NHEADS, 256, 0, stream>>>(Sbuf, pcum);
    chunk_back<<<BATCH * NHEADS * NC, 256, 0, stream>>>(zx, Sbuf, pcum, Dp, ybuf);
    // 4) gate + RMSNorm -> yf (bf16)
    gate_kernel<<<ROWS, 256, 0, stream>>>(ybuf, zx, nw, yf);
    // 5) out_proj GEMM -> mamba (f32); fused convert w_fc2 -> wbf2
    gemm_p<0><<<8 * 32, 512, 0, stream>>>(
        yf, wbo, ROWS, DMODEL, DINNER, 32, mamba, nullptr, nullptr, nullptr, nullptr,
        w_fc2, wbf2, (DMODEL * INTER) / 4);
    // 6) fc1 GEMM + gelu -> gelu (bf16, aliases zx)
    gemm_p<1><<<32 * 32, 512, 0, stream>>>(
        h_bf, wbf1, ROWS, INTER, DMODEL, 32, nullptr, gelu, fc1_b, nullptr, nullptr,
        nullptr, nullptr, 0);
    // 7) fc2 GEMM + bias + mamba + residual -> d_out (f32)
    gemm_p<2><<<8 * 32, 512, 0, stream>>>(
        gelu, wbf2, ROWS, DMODEL, INTER, 32, outF, nullptr, fc2_b, mamba, hid,
        nullptr, nullptr, 0);
}

// Round 11
// 791.258 us; speedup vs baseline: 1.0949x; 1.0404x over previous
//
#include <hip/hip_runtime.h>
#include <hip/hip_bf16.h>

#define BATCH 2
#define SEQ   2048
#define DMODEL 2048
#define DINNER 4096
#define DXB   1024
#define NHEADS 64
#define NKV   16
#define HEADDIM 64
#define DSTATE 64
#define INTER 8192
#define DINPROJ 10304   // 4096 z + 1024 x + 1024 B + 4096 C + 64 dt
#define ROWS  (BATCH*SEQ)   // 4096
#define NC    32            // chunks per sequence
#define EPSV  1e-5f

typedef short short8 __attribute__((ext_vector_type(8)));
typedef float f32x4 __attribute__((ext_vector_type(4)));

typedef const __attribute__((address_space(1))) unsigned int cg_u32;
typedef __attribute__((address_space(3))) unsigned int ls_u32;

static __device__ __forceinline__ void gll16(const void* g, void* l) {
    __builtin_amdgcn_global_load_lds((cg_u32*)g, (ls_u32*)l, 16, 0, 0);
}

static __device__ __forceinline__ unsigned short f2bf(float f) {
    unsigned int u = __float_as_uint(f);
    unsigned int r = (u + 0x7fffu + ((u >> 16) & 1u)) >> 16;
    return (unsigned short)r;
}
static __device__ __forceinline__ float bf2f(unsigned short h) {
    return __uint_as_float(((unsigned int)h) << 16);
}

// ---------------- all-weights f32 -> bf16 conversion, one dispatch ----------------
__global__ __launch_bounds__(256) void conv4(const float* __restrict__ s0, unsigned short* __restrict__ d0, int n0,
                                             const float* __restrict__ s1, unsigned short* __restrict__ d1, int n1,
                                             const float* __restrict__ s2, unsigned short* __restrict__ d2, int n2,
                                             const float* __restrict__ s3, unsigned short* __restrict__ d3, int n3) {
    int gtid = blockIdx.x * 256 + threadIdx.x;
    int gstr = gridDim.x * 256;
    #define CSEG(S, D, N)                                         \
    for (int i = gtid; i < (N); i += gstr) {                      \
        float4 v = ((const float4*)(S))[i];                       \
        ushort4 o;                                                \
        o.x = f2bf(v.x); o.y = f2bf(v.y);                         \
        o.z = f2bf(v.z); o.w = f2bf(v.w);                         \
        ((ushort4*)(D))[i] = o;                                   \
    }
    CSEG(s0, d0, n0)
    CSEG(s1, d1, n1)
    CSEG(s2, d2, n2)
    CSEG(s3, d3, n3)
    #undef CSEG
}

// ---------------- LayerNorm: one block per row, writes bf16 h ----------------
__global__ __launch_bounds__(256) void ln_kernel(const float* __restrict__ x,
                                                 const float* __restrict__ w,
                                                 const float* __restrict__ b,
                                                 unsigned short* __restrict__ hout) {
    int row = blockIdx.x;
    int t = threadIdx.x;
    const float* xr = x + (size_t)row * DMODEL;
    float v[8];
    float4 v0 = *(const float4*)&xr[t * 8];
    float4 v1 = *(const float4*)&xr[t * 8 + 4];
    v[0]=v0.x; v[1]=v0.y; v[2]=v0.z; v[3]=v0.w; v[4]=v1.x; v[5]=v1.y; v[6]=v1.z; v[7]=v1.w;
    float s = 0.f, s2 = 0.f;
    #pragma unroll
    for (int i = 0; i < 8; ++i) { s += v[i]; s2 += v[i]*v[i]; }
    #pragma unroll
    for (int off = 1; off < 64; off <<= 1) { s += __shfl_xor(s, off); s2 += __shfl_xor(s2, off); }
    __shared__ float sa[4], sb[4];
    int lane = t & 63, wv = t >> 6;
    if (lane == 0) { sa[wv] = s; sb[wv] = s2; }
    __syncthreads();
    s = sa[0]+sa[1]+sa[2]+sa[3];
    s2 = sb[0]+sb[1]+sb[2]+sb[3];
    float mu = s / DMODEL;
    float var = s2 / DMODEL - mu * mu;
    float sc = rsqrtf(var + EPSV);
    unsigned short* ho = hout + (size_t)row * DMODEL + t * 8;
    #pragma unroll
    for (int i = 0; i < 8; ++i) {
        int d = t * 8 + i;
        ho[i] = f2bf((v[i] - mu) * sc * w[d] + b[d]);
    }
}

// ---------------- pipelined bf16 MFMA GEMM: C[M,N] = A[M,K] * B[N,K]^T ----------
// R5/R8 best-known skeleton: 128x256 tile, BK=64, 8 waves (2x4), ring-3 LDS
// (144KB), global_load_lds staging with pre-swizzled source (T2), counted
// vmcnt(6) + 1 barrier per K-tile (T4), setprio (T5), by-fast XCD swizzle (T1).
// Compute: mfma_f32_16x16x32_bf16 (4x4 frags, verified 0 LDS conflicts).
// EPI 0: f32. EPI 1: gelu(acc+bias)->bf16. EPI 2: acc+bias+add1+add2->f32. EPI 3: bf16.
#define SLOTSZ 49152
template <int EPI>
__global__ __launch_bounds__(512, 2) void gemm_p(
    const unsigned short* __restrict__ A, const unsigned short* __restrict__ B,
    int M, int N, int K, int nby,
    float* __restrict__ outF, unsigned short* __restrict__ outH,
    const float* __restrict__ bias, const float* __restrict__ add1,
    const float* __restrict__ add2) {
    __shared__ __align__(16) char smem[3 * SLOTSZ];
    int t = threadIdx.x, lane = t & 63, w = t >> 6;
    int nwg = gridDim.x, cpx = nwg >> 3;
    int logical = (blockIdx.x & 7) * cpx + (blockIdx.x >> 3);
    int by = logical % nby, bx = logical / nby;   // by-fast: B-tile reuse in L2
    int brow = by * 128, bcol = bx * 256;
    int wr = w >> 2, wc = w & 3;
    int wrb = wr * 64, wcb = wc * 64;

    // staging source (swizzled): lane l fetches row (l>>3), chunk (l&7)^(l>>3)
    int lr8 = lane >> 3;
    int lch = ((lane & 7) ^ lr8) << 3;          // element offset within 64-elem row
    const unsigned short* pa[2];
    #pragma unroll
    for (int j = 0; j < 2; ++j)
        pa[j] = A + (size_t)(brow + w * 16 + j * 8 + lr8) * K + lch;
    const unsigned short* pb[4];
    #pragma unroll
    for (int j = 0; j < 4; ++j) {
        int r = bcol + w * 32 + j * 8 + lr8;
        if (r > N - 1) r = N - 1;
        pb[j] = B + (size_t)r * K + lch;
    }
    auto stageA = [&](int slot, int j) {
        gll16(pa[j], smem + slot * SLOTSZ + (w * 16 + j * 8) * 128);
        pa[j] += 64;
    };
    auto stageB = [&](int slot, int j) {
        gll16(pb[j], smem + slot * SLOTSZ + 16384 + (w * 32 + j * 8) * 128);
        pb[j] += 64;
    };

    // fragment-read swizzle: byte = row*128 + ((c ^ (row&7))*16), c = ks*4 + (lane>>4)
    int arow = lane & 15;
    int swz0 = (((lane >> 4) ^ (lane & 7)) << 4);

    f32x4 acc[4][4] = {};
    const int NT = K >> 6;
    #pragma unroll
    for (int j = 0; j < 2; ++j) stageA(0, j);
    #pragma unroll
    for (int j = 0; j < 4; ++j) stageB(0, j);
    #pragma unroll
    for (int j = 0; j < 2; ++j) stageA(1, j);
    #pragma unroll
    for (int j = 0; j < 4; ++j) stageB(1, j);

    int slot = 0, slot2 = 2;
    for (int kt = 0; kt < NT; ++kt) {
        if (kt + 1 < NT) { asm volatile("s_waitcnt vmcnt(6)" ::: "memory"); }
        else             { asm volatile("s_waitcnt vmcnt(0)" ::: "memory"); }
        __builtin_amdgcn_s_barrier();
        asm volatile("" ::: "memory");
        const char* Ab = smem + slot * SLOTSZ;
        const char* Bb = Ab + 16384;
        bool st = (kt + 2 < NT);
        // ---- phase 0 (k 0..31) ----
        short8 af[4], bfv[4];
        #pragma unroll
        for (int f = 0; f < 4; ++f)
            af[f] = *(const short8*)(Ab + (wrb + f * 16 + arow) * 128 + swz0);
        #pragma unroll
        for (int n = 0; n < 4; ++n)
            bfv[n] = *(const short8*)(Bb + (wcb + n * 16 + arow) * 128 + swz0);
        if (st) { stageA(slot2, 0); stageA(slot2, 1); stageB(slot2, 0); }
        __builtin_amdgcn_s_setprio(1);
        #pragma unroll
        for (int f = 0; f < 4; ++f)
            #pragma unroll
            for (int n = 0; n < 4; ++n)
                acc[f][n] = __builtin_amdgcn_mfma_f32_16x16x32_bf16(af[f], bfv[n], acc[f][n], 0, 0, 0);
        __builtin_amdgcn_s_setprio(0);
        // ---- phase 1 (k 32..63) ----
        #pragma unroll
        for (int f = 0; f < 4; ++f)
            af[f] = *(const short8*)(Ab + (wrb + f * 16 + arow) * 128 + (swz0 ^ 64));
        #pragma unroll
        for (int n = 0; n < 4; ++n)
            bfv[n] = *(const short8*)(Bb + (wcb + n * 16 + arow) * 128 + (swz0 ^ 64));
        if (st) { stageB(slot2, 1); stageB(slot2, 2); stageB(slot2, 3); }
        __builtin_amdgcn_s_setprio(1);
        #pragma unroll
        for (int f = 0; f < 4; ++f)
            #pragma unroll
            for (int n = 0; n < 4; ++n)
                acc[f][n] = __builtin_amdgcn_mfma_f32_16x16x32_bf16(af[f], bfv[n], acc[f][n], 0, 0, 0);
        __builtin_amdgcn_s_setprio(0);
        slot  = (slot  == 2) ? 0 : slot + 1;
        slot2 = (slot2 == 2) ? 0 : slot2 + 1;
    }

    int rlane = (lane >> 4) << 2, clane = lane & 15;
    #pragma unroll
    for (int f = 0; f < 4; ++f) {
        #pragma unroll
        for (int n = 0; n < 4; ++n) {
            int col = bcol + wcb + n * 16 + clane;
            if (col < N) {
                #pragma unroll
                for (int j = 0; j < 4; ++j) {
                    int row = brow + wrb + f * 16 + rlane + j;
                    size_t idx = (size_t)row * N + col;
                    float v = acc[f][n][j];
                    if constexpr (EPI == 0) {
                        outF[idx] = v;
                    } else if constexpr (EPI == 1) {
                        v += bias[col];
                        float g = 0.5f * v * (1.f + tanhf(0.7978845608f * (v + 0.044715f * v * v * v)));
                        outH[idx] = f2bf(g);
                    } else if constexpr (EPI == 2) {
                        outF[idx] = v + bias[col] + add1[idx] + add2[idx];
                    } else {
                        outH[idx] = f2bf(v);
                    }
                }
            }
        }
    }
}

// 64x64x64 bf16 MFMA: out rows = rows of Al, out cols = rows of Bl, K = inner 64.
static __device__ __forceinline__ void mm64(const unsigned short* Al, const unsigned short* Bl,
                                            f32x4* acc, int w, int lane) {
    int lr = lane & 15, kg = (lane >> 4) << 3;
    #pragma unroll
    for (int ks = 0; ks < 2; ++ks) {
        short8 a = *(const short8*)&Al[(w * 16 + lr) * 64 + ks * 32 + kg];
        #pragma unroll
        for (int fn = 0; fn < 4; ++fn) {
            short8 bb = *(const short8*)&Bl[(fn * 16 + lr) * 64 + ks * 32 + kg];
            acc[fn] = __builtin_amdgcn_mfma_f32_16x16x32_bf16(a, bb, acc[fn], 0, 0, 0);
        }
    }
}

// ---------------- K1: per-(b,h,chunk) intra-chunk work (dt fused) ----------------
__global__ __launch_bounds__(256) void chunk_front(const unsigned short* __restrict__ zx,
                                                   const float* __restrict__ dt_bias,
                                                   const float* __restrict__ A_log,
                                                   float* __restrict__ pcum,
                                                   unsigned short* __restrict__ ybuf,
                                                   unsigned short* __restrict__ Sbuf) {
    __shared__ __align__(16) unsigned short Cs[64*64], Bsr[64*64], Btr[64*64],
                                            Xtr[64*64], Xw[64*64], Wsm[64*64];
    __shared__ float dts[64], clg[64];
    int t = threadIdx.x, lane = t & 63, w = t >> 6;
    int bid = blockIdx.x;
    int c = bid & 31, h = (bid >> 5) & 63, b = bid >> 11, g = h >> 2;
    int row0 = (b << 11) + (c << 6);

    if (t < 64) {
        float raw = bf2f(zx[(size_t)(row0 + t) * DINPROJ + 10240 + h]) + dt_bias[h];
        float dt = raw > 20.f ? raw : log1pf(expf(raw));
        dts[t] = dt;
        float v = dt * (-expf(A_log[h]));
        #pragma unroll
        for (int off = 1; off < 64; off <<= 1) {
            float o = __shfl_up(v, off);
            if (lane >= off) v += o;
        }
        clg[t] = v;
        pcum[(size_t)(row0 + t) * 64 + h] = expf(v);
    }
    ushort4 xr[4];
    #pragma unroll
    for (int i = 0; i < 4; ++i) {
        int q = i * 256 + t, s = q >> 4, d4 = (q & 15) << 2;
        const unsigned short* rp = zx + (size_t)(row0 + s) * DINPROJ;
        ushort4 cv = *(const ushort4*)&rp[6144 + h * 64 + d4];
        *(ushort4*)&Cs[s * 64 + d4] = cv;
        ushort4 bv = *(const ushort4*)&rp[5120 + g * 64 + d4];
        *(ushort4*)&Bsr[s * 64 + d4] = bv;
        Btr[(d4 + 0) * 64 + s] = bv.x; Btr[(d4 + 1) * 64 + s] = bv.y;
        Btr[(d4 + 2) * 64 + s] = bv.z; Btr[(d4 + 3) * 64 + s] = bv.w;
        ushort4 xv = *(const ushort4*)&rp[4096 + g * 64 + d4];
        Xtr[(d4 + 0) * 64 + s] = xv.x; Xtr[(d4 + 1) * 64 + s] = xv.y;
        Xtr[(d4 + 2) * 64 + s] = xv.z; Xtr[(d4 + 3) * 64 + s] = xv.w;
        xr[i] = xv;
    }
    __syncthreads();
    float cl63 = clg[63];
    #pragma unroll
    for (int i = 0; i < 4; ++i) {
        int q = i * 256 + t, s = q >> 4, d4 = (q & 15) << 2;
        float ws = dts[s] * expf(cl63 - clg[s]);
        Xw[(d4 + 0) * 64 + s] = f2bf(bf2f(xr[i].x) * ws);
        Xw[(d4 + 1) * 64 + s] = f2bf(bf2f(xr[i].y) * ws);
        Xw[(d4 + 2) * 64 + s] = f2bf(bf2f(xr[i].z) * ws);
        Xw[(d4 + 3) * 64 + s] = f2bf(bf2f(xr[i].w) * ws);
    }
    __syncthreads();
    f32x4 accG[4] = {};
    mm64(Cs, Bsr, accG, w, lane);
    int rl = (lane >> 4) << 2, cl = lane & 15;
    #pragma unroll
    for (int fn = 0; fn < 4; ++fn) {
        #pragma unroll
        for (int j = 0; j < 4; ++j) {
            int tr = w * 16 + rl + j, rc = fn * 16 + cl;
            float val = 0.f;
            if (rc <= tr) val = accG[fn][j] * expf(clg[tr] - clg[rc]) * dts[rc];
            Wsm[tr * 64 + rc] = f2bf(val);
        }
    }
    __syncthreads();
    f32x4 accY[4] = {};
    mm64(Wsm, Xtr, accY, w, lane);
    f32x4 accS[4] = {};
    mm64(Xw, Btr, accS, w, lane);
    size_t cb = (size_t)((((b << 6) + h) << 5) + c) * 4096;
    #pragma unroll
    for (int fn = 0; fn < 4; ++fn) {
        #pragma unroll
        for (int j = 0; j < 4; ++j) {
            int tr = w * 16 + rl + j, pc = fn * 16 + cl;
            ybuf[(size_t)(row0 + tr) * DINNER + h * 64 + pc] = f2bf(accY[fn][j]);
            Sbuf[cb + tr * 64 + pc] = f2bf(accS[fn][j]);
        }
    }
}

// ---------------- K2: inter-chunk state recurrence (in-place S -> H0) ----------------
// 4096 state elements per (b,h) are independent recurrences over c: split each
// (b,h) across 4 blocks (512 blocks total) for full-chip occupancy.
__global__ __launch_bounds__(256) void chunk_state(unsigned short* __restrict__ SH,
                                                   const float* __restrict__ pcum) {
    int bid = blockIdx.x;            // (b,h,q): q = bid&3
    int q = bid & 3, bh = bid >> 2;
    int b = bh >> 6, h = bh & 63;
    int t = threadIdx.x;
    float H[4];
    #pragma unroll
    for (int j = 0; j < 4; ++j) H[j] = 0.f;
    for (int c = 0; c < NC; ++c) {
        size_t base = (size_t)((((b << 6) + h) << 5) + c) * 4096 + q * 1024;
        float Tc = pcum[(size_t)((b << 11) + (c << 6) + 63) * 64 + h];
        #pragma unroll
        for (int j = 0; j < 4; ++j) {
            int e = j * 256 + t;
            unsigned short sv = SH[base + e];
            SH[base + e] = f2bf(H[j]);
            H[j] = H[j] * Tc + bf2f(sv);
        }
    }
}

// ---------------- K3: y += p_t * (C_t . H0) + Dp * x ----------------
__global__ __launch_bounds__(256) void chunk_back(const unsigned short* __restrict__ zx,
                                                  const unsigned short* __restrict__ SH,
                                                  const float* __restrict__ pcum,
                                                  const float* __restrict__ Dp,
                                                  unsigned short* __restrict__ ybuf) {
    __shared__ __align__(16) unsigned short Cs[64*64], Hs[64*64];
    __shared__ float ps[64];
    int t = threadIdx.x, lane = t & 63, w = t >> 6;
    int bid = blockIdx.x;
    int c = bid & 31, h = (bid >> 5) & 63, b = bid >> 11, g = h >> 2;
    int row0 = (b << 11) + (c << 6);
    size_t cb = (size_t)((((b << 6) + h) << 5) + c) * 4096;
    #pragma unroll
    for (int i = 0; i < 4; ++i) {
        int q = i * 256 + t, s = q >> 4, d4 = (q & 15) << 2;
        *(ushort4*)&Cs[s * 64 + d4] =
            *(const ushort4*)&zx[(size_t)(row0 + s) * DINPROJ + 6144 + h * 64 + d4];
        *(ushort4*)&Hs[s * 64 + d4] = *(const ushort4*)&SH[cb + s * 64 + d4];
    }
    if (t < 64) ps[t] = pcum[(size_t)(row0 + t) * 64 + h];
    __syncthreads();
    f32x4 acc[4] = {};
    mm64(Cs, Hs, acc, w, lane);
    float Dph = Dp[h];
    int rl = (lane >> 4) << 2, cl = lane & 15;
    #pragma unroll
    for (int fn = 0; fn < 4; ++fn) {
        #pragma unroll
        for (int j = 0; j < 4; ++j) {
            int tr = w * 16 + rl + j, pc = fn * 16 + cl;
            size_t yi = (size_t)(row0 + tr) * DINNER + h * 64 + pc;
            float xv = bf2f(zx[(size_t)(row0 + tr) * DINPROJ + 4096 + g * 64 + pc]);
            ybuf[yi] = f2bf(bf2f(ybuf[yi]) + acc[fn][j] * ps[tr] + Dph * xv);
        }
    }
}

// ---------------- gate (silu) + RMSNorm -> bf16 yf ----------------
__global__ __launch_bounds__(256) void gate_kernel(const unsigned short* __restrict__ y,
                                                   const unsigned short* __restrict__ zx,
                                                   const float* __restrict__ norm_w,
                                                   unsigned short* __restrict__ yf) {
    int row = blockIdx.x;
    int t = threadIdx.x;
    float v[16];
    float s2 = 0.f;
    #pragma unroll
    for (int i = 0; i < 16; ++i) {
        int d = i * 256 + t;
        float yv = bf2f(y[(size_t)row * DINNER + d]);
        float zv = bf2f(zx[(size_t)row * DINPROJ + d]);
        float gt = zv / (1.f + expf(-zv));
        v[i] = yv * gt;
        s2 += v[i] * v[i];
    }
    #pragma unroll
    for (int off = 1; off < 64; off <<= 1) s2 += __shfl_xor(s2, off);
    __shared__ float sb[4];
    int lane = t & 63, wv = t >> 6;
    if (lane == 0) sb[wv] = s2;
    __syncthreads();
    s2 = sb[0] + sb[1] + sb[2] + sb[3];
    float sc = rsqrtf(s2 / DINNER + EPSV);
    #pragma unroll
    for (int i = 0; i < 16; ++i) {
        int d = i * 256 + t;
        yf[(size_t)row * DINNER + d] = f2bf(v[i] * sc * norm_w[d]);
    }
}

extern "C" void kernel_launch(void* const* d_in, const int* in_sizes, int n_in,
                              void* d_out, int out_size, void* d_ws, size_t ws_size,
                              hipStream_t stream) {
    const float* hid   = (const float*)d_in[0];
    const float* ln_w  = (const float*)d_in[1];
    const float* ln_b  = (const float*)d_in[2];
    const float* w_inp = (const float*)d_in[3];
    const float* dtb   = (const float*)d_in[4];
    const float* A_log = (const float*)d_in[5];
    const float* Dp    = (const float*)d_in[6];
    const float* nw    = (const float*)d_in[7];
    const float* w_out = (const float*)d_in[8];
    const float* w_fc1 = (const float*)d_in[9];
    const float* fc1_b = (const float*)d_in[10];
    const float* w_fc2 = (const float*)d_in[11];
    const float* fc2_b = (const float*)d_in[12];

    char* ws = (char*)d_ws;
    size_t off = 0;
    auto alloc = [&](size_t bytes) { size_t o = off; off += (bytes + 255) & ~(size_t)255; return o; };
    size_t o_h    = alloc((size_t)ROWS * DMODEL * 2);        // h bf16
    size_t o_wi   = alloc((size_t)DINPROJ * DMODEL * 2);     // w_inp bf16
    size_t o_wo   = alloc((size_t)DMODEL * DINNER * 2);      // w_out bf16
    size_t o_wf1  = alloc((size_t)INTER * DMODEL * 2);       // w_fc1 bf16
    size_t o_wf2  = alloc((size_t)DMODEL * INTER * 2);       // w_fc2 bf16
    size_t o_zx   = alloc((size_t)ROWS * DINPROJ * 2);       // zxbcdt bf16 (later: gelu bf16)
    size_t o_pc   = alloc((size_t)ROWS * NHEADS * 4);        // pcum f32
    size_t o_y    = alloc((size_t)ROWS * DINNER * 2);        // y bf16 (later: mamba f32 area reuse)
    size_t o_yf   = alloc((size_t)ROWS * DINNER * 2);        // yf bf16
    size_t o_S    = alloc((size_t)BATCH * NHEADS * NC * HEADDIM * DSTATE * 2); // S->H0 bf16

    unsigned short* h_bf  = (unsigned short*)(ws + o_h);
    unsigned short* wbi   = (unsigned short*)(ws + o_wi);
    unsigned short* wbo   = (unsigned short*)(ws + o_wo);
    unsigned short* wbf1  = (unsigned short*)(ws + o_wf1);
    unsigned short* wbf2  = (unsigned short*)(ws + o_wf2);
    unsigned short* zx    = (unsigned short*)(ws + o_zx);
    float* pcum           = (float*)(ws + o_pc);
    unsigned short* ybuf  = (unsigned short*)(ws + o_y);
    unsigned short* yf    = (unsigned short*)(ws + o_yf);
    unsigned short* Sbuf  = (unsigned short*)(ws + o_S);
    unsigned short* gelu  = (unsigned short*)(ws + o_zx);    // alias: zx dead after gate
    float* mamba          = (float*)(ws + o_y);              // alias: y dead after gate
    float* outF           = (float*)d_out;

    // 0) all weight conversions in one dispatch
    conv4<<<2048, 256, 0, stream>>>(
        w_inp, wbi,  (DINPROJ * DMODEL) / 4,
        w_out, wbo,  (DMODEL * DINNER) / 4,
        w_fc1, wbf1, (INTER * DMODEL) / 4,
        w_fc2, wbf2, (DMODEL * INTER) / 4);
    // 1) LayerNorm -> h (bf16)
    ln_kernel<<<ROWS, 256, 0, stream>>>(hid, ln_w, ln_b, h_bf);
    // 2) in_proj GEMM -> zx (bf16); grid = 41 col-tiles x 32 row-tiles
    gemm_p<3><<<41 * 32, 512, 0, stream>>>(
        h_bf, wbi, ROWS, DINPROJ, DMODEL, 32, nullptr, zx, nullptr, nullptr, nullptr);
    // 3) chunked SSD scan (dt softplus fused into chunk_front)
    chunk_front<<<BATCH * NHEADS * NC, 256, 0, stream>>>(zx, dtb, A_log, pcum, ybuf, Sbuf);
    chunk_state<<<BATCH * NHEADS * 4, 256, 0, stream>>>(Sbuf, pcum);
    chunk_back<<<BATCH * NHEADS * NC, 256, 0, stream>>>(zx, Sbuf, pcum, Dp, ybuf);
    // 4) gate + RMSNorm -> yf (bf16)
    gate_kernel<<<ROWS, 256, 0, stream>>>(ybuf, zx, nw, yf);
    // 5) out_proj GEMM -> mamba (f32)
    gemm_p<0><<<8 * 32, 512, 0, stream>>>(
        yf, wbo, ROWS, DMODEL, DINNER, 32, mamba, nullptr, nullptr, nullptr, nullptr);
    // 6) fc1 GEMM + gelu -> gelu (bf16, aliases zx)
    gemm_p<1><<<32 * 32, 512, 0, stream>>>(
        h_bf, wbf1, ROWS, INTER, DMODEL, 32, nullptr, gelu, fc1_b, nullptr, nullptr);
    // 7) fc2 GEMM + bias + mamba + residual -> d_out (f32)
    gemm_p<2><<<8 * 32, 512, 0, stream>>>(
        gelu, wbf2, ROWS, DMODEL, INTER, 32, outF, nullptr, fc2_b, mamba, hid);
}

// Round 12
// 776.455 us; speedup vs baseline: 1.1158x; 1.0191x over previous
//
#include <hip/hip_runtime.h>
#include <hip/hip_bf16.h>

#define BATCH 2
#define SEQ   2048
#define DMODEL 2048
#define DINNER 4096
#define DXB   1024
#define NHEADS 64
#define NKV   16
#define HEADDIM 64
#define DSTATE 64
#define INTER 8192
#define DINPROJ 10304   // 4096 z + 1024 x + 1024 B + 4096 C + 64 dt
#define ROWS  (BATCH*SEQ)   // 4096
#define NC    32            // chunks per sequence
#define EPSV  1e-5f

typedef short short8 __attribute__((ext_vector_type(8)));
typedef float f32x4 __attribute__((ext_vector_type(4)));

typedef const __attribute__((address_space(1))) unsigned int cg_u32;
typedef __attribute__((address_space(3))) unsigned int ls_u32;

static __device__ __forceinline__ void gll16(const void* g, void* l) {
    __builtin_amdgcn_global_load_lds((cg_u32*)g, (ls_u32*)l, 16, 0, 0);
}

static __device__ __forceinline__ unsigned short f2bf(float f) {
    unsigned int u = __float_as_uint(f);
    unsigned int r = (u + 0x7fffu + ((u >> 16) & 1u)) >> 16;
    return (unsigned short)r;
}
static __device__ __forceinline__ float bf2f(unsigned short h) {
    return __uint_as_float(((unsigned int)h) << 16);
}

// ---------------- all-weights f32 -> bf16 conversion, one dispatch ----------------
__global__ __launch_bounds__(256) void conv4(const float* __restrict__ s0, unsigned short* __restrict__ d0, int n0,
                                             const float* __restrict__ s1, unsigned short* __restrict__ d1, int n1,
                                             const float* __restrict__ s2, unsigned short* __restrict__ d2, int n2,
                                             const float* __restrict__ s3, unsigned short* __restrict__ d3, int n3) {
    int gtid = blockIdx.x * 256 + threadIdx.x;
    int gstr = gridDim.x * 256;
    #define CSEG(S, D, N)                                         \
    for (int i = gtid; i < (N); i += gstr) {                      \
        float4 v = ((const float4*)(S))[i];                       \
        ushort4 o;                                                \
        o.x = f2bf(v.x); o.y = f2bf(v.y);                         \
        o.z = f2bf(v.z); o.w = f2bf(v.w);                         \
        ((ushort4*)(D))[i] = o;                                   \
    }
    CSEG(s0, d0, n0)
    CSEG(s1, d1, n1)
    CSEG(s2, d2, n2)
    CSEG(s3, d3, n3)
    #undef CSEG
}

// ---------------- LayerNorm: one block per row, writes bf16 h ----------------
__global__ __launch_bounds__(256) void ln_kernel(const float* __restrict__ x,
                                                 const float* __restrict__ w,
                                                 const float* __restrict__ b,
                                                 unsigned short* __restrict__ hout) {
    int row = blockIdx.x;
    int t = threadIdx.x;
    const float* xr = x + (size_t)row * DMODEL;
    float v[8];
    float4 v0 = *(const float4*)&xr[t * 8];
    float4 v1 = *(const float4*)&xr[t * 8 + 4];
    v[0]=v0.x; v[1]=v0.y; v[2]=v0.z; v[3]=v0.w; v[4]=v1.x; v[5]=v1.y; v[6]=v1.z; v[7]=v1.w;
    float s = 0.f, s2 = 0.f;
    #pragma unroll
    for (int i = 0; i < 8; ++i) { s += v[i]; s2 += v[i]*v[i]; }
    #pragma unroll
    for (int off = 1; off < 64; off <<= 1) { s += __shfl_xor(s, off); s2 += __shfl_xor(s2, off); }
    __shared__ float sa[4], sb[4];
    int lane = t & 63, wv = t >> 6;
    if (lane == 0) { sa[wv] = s; sb[wv] = s2; }
    __syncthreads();
    s = sa[0]+sa[1]+sa[2]+sa[3];
    s2 = sb[0]+sb[1]+sb[2]+sb[3];
    float mu = s / DMODEL;
    float var = s2 / DMODEL - mu * mu;
    float sc = rsqrtf(var + EPSV);
    unsigned short* ho = hout + (size_t)row * DMODEL + t * 8;
    #pragma unroll
    for (int i = 0; i < 8; ++i) {
        int d = t * 8 + i;
        ho[i] = f2bf((v[i] - mu) * sc * w[d] + b[d]);
    }
}

// ---------------- pipelined bf16 MFMA GEMM: C[M,N] = A[M,K] * B[N,K]^T ----------
// R5/R8 best-known skeleton: 128x256 tile, BK=64, 8 waves (2x4), ring-3 LDS
// (144KB), global_load_lds staging with pre-swizzled source (T2), counted
// vmcnt(6) + 1 barrier per K-tile (T4), setprio (T5), by-fast XCD swizzle (T1).
// Compute: mfma_f32_16x16x32_bf16 (4x4 frags, verified 0 LDS conflicts).
// Dual-source K: segment 1 = (A,B) with row-stride K1, segment 2 = (A2,B2)
// with row-stride K-K1; staging pointers rebase when the staged tile crosses
// K1 (scalar-uniform branch). Pass A2=B2=nullptr, K1=K for single-source.
// EPI 0: f32. EPI 1: gelu(acc+bias)->bf16. EPI 2: acc+bias+add1+add2->f32.
// EPI 3: bf16. EPI 4: acc+bias+add2->f32.
#define SLOTSZ 49152
template <int EPI>
__global__ __launch_bounds__(512, 2) void gemm_p(
    const unsigned short* __restrict__ A, const unsigned short* __restrict__ B,
    int M, int N, int K, int nby,
    float* __restrict__ outF, unsigned short* __restrict__ outH,
    const float* __restrict__ bias, const float* __restrict__ add1,
    const float* __restrict__ add2,
    const unsigned short* __restrict__ A2, const unsigned short* __restrict__ B2,
    int K1) {
    __shared__ __align__(16) char smem[3 * SLOTSZ];
    int t = threadIdx.x, lane = t & 63, w = t >> 6;
    int nwg = gridDim.x, cpx = nwg >> 3;
    int logical = (blockIdx.x & 7) * cpx + (blockIdx.x >> 3);
    int by = logical % nby, bx = logical / nby;   // by-fast: B-tile reuse in L2
    int brow = by * 128, bcol = bx * 256;
    int wr = w >> 2, wc = w & 3;
    int wrb = wr * 64, wcb = wc * 64;

    // staging source (swizzled): lane l fetches row (l>>3), chunk (l&7)^(l>>3)
    int lr8 = lane >> 3;
    int lch = ((lane & 7) ^ lr8) << 3;          // element offset within 64-elem row
    const unsigned short* pa[2];
    #pragma unroll
    for (int j = 0; j < 2; ++j)
        pa[j] = A + (size_t)(brow + w * 16 + j * 8 + lr8) * K1 + lch;
    const unsigned short* pb[4];
    #pragma unroll
    for (int j = 0; j < 4; ++j) {
        int r = bcol + w * 32 + j * 8 + lr8;
        if (r > N - 1) r = N - 1;
        pb[j] = B + (size_t)r * K1 + lch;
    }
    auto stageA = [&](int slot, int j) {
        gll16(pa[j], smem + slot * SLOTSZ + (w * 16 + j * 8) * 128);
        pa[j] += 64;
    };
    auto stageB = [&](int slot, int j) {
        gll16(pb[j], smem + slot * SLOTSZ + 16384 + (w * 32 + j * 8) * 128);
        pb[j] += 64;
    };

    // fragment-read swizzle: byte = row*128 + ((c ^ (row&7))*16), c = ks*4 + (lane>>4)
    int arow = lane & 15;
    int swz0 = (((lane >> 4) ^ (lane & 7)) << 4);

    f32x4 acc[4][4] = {};
    const int NT = K >> 6;
    const int KS = K1 >> 6;      // tile index where segment 2 begins
    #pragma unroll
    for (int j = 0; j < 2; ++j) stageA(0, j);
    #pragma unroll
    for (int j = 0; j < 4; ++j) stageB(0, j);
    #pragma unroll
    for (int j = 0; j < 2; ++j) stageA(1, j);
    #pragma unroll
    for (int j = 0; j < 4; ++j) stageB(1, j);

    int slot = 0, slot2 = 2;
    for (int kt = 0; kt < NT; ++kt) {
        if (kt + 1 < NT) { asm volatile("s_waitcnt vmcnt(6)" ::: "memory"); }
        else             { asm volatile("s_waitcnt vmcnt(0)" ::: "memory"); }
        __builtin_amdgcn_s_barrier();
        asm volatile("" ::: "memory");
        const char* Ab = smem + slot * SLOTSZ;
        const char* Bb = Ab + 16384;
        bool st = (kt + 2 < NT);
        // rebase staging pointers at the K-segment boundary (uniform branch)
        if (B2 != nullptr && kt + 2 == KS) {
            int ld2 = K - K1;
            #pragma unroll
            for (int j = 0; j < 2; ++j)
                pa[j] = A2 + (size_t)(brow + w * 16 + j * 8 + lr8) * ld2 + lch;
            #pragma unroll
            for (int j = 0; j < 4; ++j) {
                int r = bcol + w * 32 + j * 8 + lr8;
                if (r > N - 1) r = N - 1;
                pb[j] = B2 + (size_t)r * ld2 + lch;
            }
        }
        // ---- phase 0 (k 0..31) ----
        short8 af[4], bfv[4];
        #pragma unroll
        for (int f = 0; f < 4; ++f)
            af[f] = *(const short8*)(Ab + (wrb + f * 16 + arow) * 128 + swz0);
        #pragma unroll
        for (int n = 0; n < 4; ++n)
            bfv[n] = *(const short8*)(Bb + (wcb + n * 16 + arow) * 128 + swz0);
        if (st) { stageA(slot2, 0); stageA(slot2, 1); stageB(slot2, 0); }
        __builtin_amdgcn_s_setprio(1);
        #pragma unroll
        for (int f = 0; f < 4; ++f)
            #pragma unroll
            for (int n = 0; n < 4; ++n)
                acc[f][n] = __builtin_amdgcn_mfma_f32_16x16x32_bf16(af[f], bfv[n], acc[f][n], 0, 0, 0);
        __builtin_amdgcn_s_setprio(0);
        // ---- phase 1 (k 32..63) ----
        #pragma unroll
        for (int f = 0; f < 4; ++f)
            af[f] = *(const short8*)(Ab + (wrb + f * 16 + arow) * 128 + (swz0 ^ 64));
        #pragma unroll
        for (int n = 0; n < 4; ++n)
            bfv[n] = *(const short8*)(Bb + (wcb + n * 16 + arow) * 128 + (swz0 ^ 64));
        if (st) { stageB(slot2, 1); stageB(slot2, 2); stageB(slot2, 3); }
        __builtin_amdgcn_s_setprio(1);
        #pragma unroll
        for (int f = 0; f < 4; ++f)
            #pragma unroll
            for (int n = 0; n < 4; ++n)
                acc[f][n] = __builtin_amdgcn_mfma_f32_16x16x32_bf16(af[f], bfv[n], acc[f][n], 0, 0, 0);
        __builtin_amdgcn_s_setprio(0);
        slot  = (slot  == 2) ? 0 : slot + 1;
        slot2 = (slot2 == 2) ? 0 : slot2 + 1;
    }

    int rlane = (lane >> 4) << 2, clane = lane & 15;
    #pragma unroll
    for (int f = 0; f < 4; ++f) {
        #pragma unroll
        for (int n = 0; n < 4; ++n) {
            int col = bcol + wcb + n * 16 + clane;
            if (col < N) {
                #pragma unroll
                for (int j = 0; j < 4; ++j) {
                    int row = brow + wrb + f * 16 + rlane + j;
                    size_t idx = (size_t)row * N + col;
                    float v = acc[f][n][j];
                    if constexpr (EPI == 0) {
                        outF[idx] = v;
                    } else if constexpr (EPI == 1) {
                        v += bias[col];
                        float g = 0.5f * v * (1.f + tanhf(0.7978845608f * (v + 0.044715f * v * v * v)));
                        outH[idx] = f2bf(g);
                    } else if constexpr (EPI == 2) {
                        outF[idx] = v + bias[col] + add1[idx] + add2[idx];
                    } else if constexpr (EPI == 4) {
                        outF[idx] = v + bias[col] + add2[idx];
                    } else {
                        outH[idx] = f2bf(v);
                    }
                }
            }
        }
    }
}

// 64x64x64 bf16 MFMA: out rows = rows of Al, out cols = rows of Bl, K = inner 64.
static __device__ __forceinline__ void mm64(const unsigned short* Al, const unsigned short* Bl,
                                            f32x4* acc, int w, int lane) {
    int lr = lane & 15, kg = (lane >> 4) << 3;
    #pragma unroll
    for (int ks = 0; ks < 2; ++ks) {
        short8 a = *(const short8*)&Al[(w * 16 + lr) * 64 + ks * 32 + kg];
        #pragma unroll
        for (int fn = 0; fn < 4; ++fn) {
            short8 bb = *(const short8*)&Bl[(fn * 16 + lr) * 64 + ks * 32 + kg];
            acc[fn] = __builtin_amdgcn_mfma_f32_16x16x32_bf16(a, bb, acc[fn], 0, 0, 0);
        }
    }
}

// ---------------- K1: per-(b,h,chunk) intra-chunk work (dt fused) ----------------
__global__ __launch_bounds__(256) void chunk_front(const unsigned short* __restrict__ zx,
                                                   const float* __restrict__ dt_bias,
                                                   const float* __restrict__ A_log,
                                                   float* __restrict__ pcum,
                                                   unsigned short* __restrict__ ybuf,
                                                   unsigned short* __restrict__ Sbuf) {
    __shared__ __align__(16) unsigned short Cs[64*64], Bsr[64*64], Btr[64*64],
                                            Xtr[64*64], Xw[64*64], Wsm[64*64];
    __shared__ float dts[64], clg[64];
    int t = threadIdx.x, lane = t & 63, w = t >> 6;
    int bid = blockIdx.x;
    int c = bid & 31, h = (bid >> 5) & 63, b = bid >> 11, g = h >> 2;
    int row0 = (b << 11) + (c << 6);

    if (t < 64) {
        float raw = bf2f(zx[(size_t)(row0 + t) * DINPROJ + 10240 + h]) + dt_bias[h];
        float dt = raw > 20.f ? raw : log1pf(expf(raw));
        dts[t] = dt;
        float v = dt * (-expf(A_log[h]));
        #pragma unroll
        for (int off = 1; off < 64; off <<= 1) {
            float o = __shfl_up(v, off);
            if (lane >= off) v += o;
        }
        clg[t] = v;
        pcum[(size_t)(row0 + t) * 64 + h] = expf(v);
    }
    ushort4 xr[4];
    #pragma unroll
    for (int i = 0; i < 4; ++i) {
        int q = i * 256 + t, s = q >> 4, d4 = (q & 15) << 2;
        const unsigned short* rp = zx + (size_t)(row0 + s) * DINPROJ;
        ushort4 cv = *(const ushort4*)&rp[6144 + h * 64 + d4];
        *(ushort4*)&Cs[s * 64 + d4] = cv;
        ushort4 bv = *(const ushort4*)&rp[5120 + g * 64 + d4];
        *(ushort4*)&Bsr[s * 64 + d4] = bv;
        Btr[(d4 + 0) * 64 + s] = bv.x; Btr[(d4 + 1) * 64 + s] = bv.y;
        Btr[(d4 + 2) * 64 + s] = bv.z; Btr[(d4 + 3) * 64 + s] = bv.w;
        ushort4 xv = *(const ushort4*)&rp[4096 + g * 64 + d4];
        Xtr[(d4 + 0) * 64 + s] = xv.x; Xtr[(d4 + 1) * 64 + s] = xv.y;
        Xtr[(d4 + 2) * 64 + s] = xv.z; Xtr[(d4 + 3) * 64 + s] = xv.w;
        xr[i] = xv;
    }
    __syncthreads();
    float cl63 = clg[63];
    #pragma unroll
    for (int i = 0; i < 4; ++i) {
        int q = i * 256 + t, s = q >> 4, d4 = (q & 15) << 2;
        float ws = dts[s] * expf(cl63 - clg[s]);
        Xw[(d4 + 0) * 64 + s] = f2bf(bf2f(xr[i].x) * ws);
        Xw[(d4 + 1) * 64 + s] = f2bf(bf2f(xr[i].y) * ws);
        Xw[(d4 + 2) * 64 + s] = f2bf(bf2f(xr[i].z) * ws);
        Xw[(d4 + 3) * 64 + s] = f2bf(bf2f(xr[i].w) * ws);
    }
    __syncthreads();
    f32x4 accG[4] = {};
    mm64(Cs, Bsr, accG, w, lane);
    int rl = (lane >> 4) << 2, cl = lane & 15;
    #pragma unroll
    for (int fn = 0; fn < 4; ++fn) {
        #pragma unroll
        for (int j = 0; j < 4; ++j) {
            int tr = w * 16 + rl + j, rc = fn * 16 + cl;
            float val = 0.f;
            if (rc <= tr) val = accG[fn][j] * expf(clg[tr] - clg[rc]) * dts[rc];
            Wsm[tr * 64 + rc] = f2bf(val);
        }
    }
    __syncthreads();
    f32x4 accY[4] = {};
    mm64(Wsm, Xtr, accY, w, lane);
    f32x4 accS[4] = {};
    mm64(Xw, Btr, accS, w, lane);
    size_t cb = (size_t)((((b << 6) + h) << 5) + c) * 4096;
    #pragma unroll
    for (int fn = 0; fn < 4; ++fn) {
        #pragma unroll
        for (int j = 0; j < 4; ++j) {
            int tr = w * 16 + rl + j, pc = fn * 16 + cl;
            ybuf[(size_t)(row0 + tr) * DINNER + h * 64 + pc] = f2bf(accY[fn][j]);
            Sbuf[cb + tr * 64 + pc] = f2bf(accS[fn][j]);
        }
    }
}

// ---------------- K2: inter-chunk state recurrence (in-place S -> H0) ----------------
__global__ __launch_bounds__(256) void chunk_state(unsigned short* __restrict__ SH,
                                                   const float* __restrict__ pcum) {
    int bid = blockIdx.x;            // (b,h,q): q = bid&3
    int q = bid & 3, bh = bid >> 2;
    int b = bh >> 6, h = bh & 63;
    int t = threadIdx.x;
    float H[4];
    #pragma unroll
    for (int j = 0; j < 4; ++j) H[j] = 0.f;
    for (int c = 0; c < NC; ++c) {
        size_t base = (size_t)((((b << 6) + h) << 5) + c) * 4096 + q * 1024;
        float Tc = pcum[(size_t)((b << 11) + (c << 6) + 63) * 64 + h];
        #pragma unroll
        for (int j = 0; j < 4; ++j) {
            int e = j * 256 + t;
            unsigned short sv = SH[base + e];
            SH[base + e] = f2bf(H[j]);
            H[j] = H[j] * Tc + bf2f(sv);
        }
    }
}

// ---------------- K3: y += p_t * (C_t . H0) + Dp * x ----------------
__global__ __launch_bounds__(256) void chunk_back(const unsigned short* __restrict__ zx,
                                                  const unsigned short* __restrict__ SH,
                                                  const float* __restrict__ pcum,
                                                  const float* __restrict__ Dp,
                                                  unsigned short* __restrict__ ybuf) {
    __shared__ __align__(16) unsigned short Cs[64*64], Hs[64*64];
    __shared__ float ps[64];
    int t = threadIdx.x, lane = t & 63, w = t >> 6;
    int bid = blockIdx.x;
    int c = bid & 31, h = (bid >> 5) & 63, b = bid >> 11, g = h >> 2;
    int row0 = (b << 11) + (c << 6);
    size_t cb = (size_t)((((b << 6) + h) << 5) + c) * 4096;
    #pragma unroll
    for (int i = 0; i < 4; ++i) {
        int q = i * 256 + t, s = q >> 4, d4 = (q & 15) << 2;
        *(ushort4*)&Cs[s * 64 + d4] =
            *(const ushort4*)&zx[(size_t)(row0 + s) * DINPROJ + 6144 + h * 64 + d4];
        *(ushort4*)&Hs[s * 64 + d4] = *(const ushort4*)&SH[cb + s * 64 + d4];
    }
    if (t < 64) ps[t] = pcum[(size_t)(row0 + t) * 64 + h];
    __syncthreads();
    f32x4 acc[4] = {};
    mm64(Cs, Hs, acc, w, lane);
    float Dph = Dp[h];
    int rl = (lane >> 4) << 2, cl = lane & 15;
    #pragma unroll
    for (int fn = 0; fn < 4; ++fn) {
        #pragma unroll
        for (int j = 0; j < 4; ++j) {
            int tr = w * 16 + rl + j, pc = fn * 16 + cl;
            size_t yi = (size_t)(row0 + tr) * DINNER + h * 64 + pc;
            float xv = bf2f(zx[(size_t)(row0 + tr) * DINPROJ + 4096 + g * 64 + pc]);
            ybuf[yi] = f2bf(bf2f(ybuf[yi]) + acc[fn][j] * ps[tr] + Dph * xv);
        }
    }
}

// ---------------- gate (silu) + RMSNorm -> bf16 yf ----------------
__global__ __launch_bounds__(256) void gate_kernel(const unsigned short* __restrict__ y,
                                                   const unsigned short* __restrict__ zx,
                                                   const float* __restrict__ norm_w,
                                                   unsigned short* __restrict__ yf) {
    int row = blockIdx.x;
    int t = threadIdx.x;
    float v[16];
    float s2 = 0.f;
    #pragma unroll
    for (int i = 0; i < 16; ++i) {
        int d = i * 256 + t;
        float yv = bf2f(y[(size_t)row * DINNER + d]);
        float zv = bf2f(zx[(size_t)row * DINPROJ + d]);
        float gt = zv / (1.f + expf(-zv));
        v[i] = yv * gt;
        s2 += v[i] * v[i];
    }
    #pragma unroll
    for (int off = 1; off < 64; off <<= 1) s2 += __shfl_xor(s2, off);
    __shared__ float sb[4];
    int lane = t & 63, wv = t >> 6;
    if (lane == 0) sb[wv] = s2;
    __syncthreads();
    s2 = sb[0] + sb[1] + sb[2] + sb[3];
    float sc = rsqrtf(s2 / DINNER + EPSV);
    #pragma unroll
    for (int i = 0; i < 16; ++i) {
        int d = i * 256 + t;
        yf[(size_t)row * DINNER + d] = f2bf(v[i] * sc * norm_w[d]);
    }
}

extern "C" void kernel_launch(void* const* d_in, const int* in_sizes, int n_in,
                              void* d_out, int out_size, void* d_ws, size_t ws_size,
                              hipStream_t stream) {
    const float* hid   = (const float*)d_in[0];
    const float* ln_w  = (const float*)d_in[1];
    const float* ln_b  = (const float*)d_in[2];
    const float* w_inp = (const float*)d_in[3];
    const float* dtb   = (const float*)d_in[4];
    const float* A_log = (const float*)d_in[5];
    const float* Dp    = (const float*)d_in[6];
    const float* nw    = (const float*)d_in[7];
    const float* w_out = (const float*)d_in[8];
    const float* w_fc1 = (const float*)d_in[9];
    const float* fc1_b = (const float*)d_in[10];
    const float* w_fc2 = (const float*)d_in[11];
    const float* fc2_b = (const float*)d_in[12];

    char* ws = (char*)d_ws;
    size_t off = 0;
    auto alloc = [&](size_t bytes) { size_t o = off; off += (bytes + 255) & ~(size_t)255; return o; };
    size_t o_h    = alloc((size_t)ROWS * DMODEL * 2);        // h bf16
    size_t o_wi   = alloc((size_t)DINPROJ * DMODEL * 2);     // w_inp bf16
    size_t o_wo   = alloc((size_t)DMODEL * DINNER * 2);      // w_out bf16
    size_t o_wf1  = alloc((size_t)INTER * DMODEL * 2);       // w_fc1 bf16
    size_t o_wf2  = alloc((size_t)DMODEL * INTER * 2);       // w_fc2 bf16
    size_t o_zx   = alloc((size_t)ROWS * DINPROJ * 2);       // zxbcdt bf16 (later: gelu bf16)
    size_t o_pc   = alloc((size_t)ROWS * NHEADS * 4);        // pcum f32
    size_t o_y    = alloc((size_t)ROWS * DINNER * 2);        // y bf16
    size_t o_yf   = alloc((size_t)ROWS * DINNER * 2);        // yf bf16
    size_t o_S    = alloc((size_t)BATCH * NHEADS * NC * HEADDIM * DSTATE * 2); // S->H0 bf16

    unsigned short* h_bf  = (unsigned short*)(ws + o_h);
    unsigned short* wbi   = (unsigned short*)(ws + o_wi);
    unsigned short* wbo   = (unsigned short*)(ws + o_wo);
    unsigned short* wbf1  = (unsigned short*)(ws + o_wf1);
    unsigned short* wbf2  = (unsigned short*)(ws + o_wf2);
    unsigned short* zx    = (unsigned short*)(ws + o_zx);
    float* pcum           = (float*)(ws + o_pc);
    unsigned short* ybuf  = (unsigned short*)(ws + o_y);
    unsigned short* yf    = (unsigned short*)(ws + o_yf);
    unsigned short* Sbuf  = (unsigned short*)(ws + o_S);
    unsigned short* gelu  = (unsigned short*)(ws + o_zx);    // alias: zx dead after gate
    float* outF           = (float*)d_out;

    // 0) all weight conversions in one dispatch
    conv4<<<2048, 256, 0, stream>>>(
        w_inp, wbi,  (DINPROJ * DMODEL) / 4,
        w_out, wbo,  (DMODEL * DINNER) / 4,
        w_fc1, wbf1, (INTER * DMODEL) / 4,
        w_fc2, wbf2, (DMODEL * INTER) / 4);
    // 1) LayerNorm -> h (bf16)
    ln_kernel<<<ROWS, 256, 0, stream>>>(hid, ln_w, ln_b, h_bf);
    // 2) in_proj GEMM -> zx (bf16); grid = 41 col-tiles x 32 row-tiles
    gemm_p<3><<<41 * 32, 512, 0, stream>>>(
        h_bf, wbi, ROWS, DINPROJ, DMODEL, 32, nullptr, zx, nullptr, nullptr, nullptr,
        nullptr, nullptr, DMODEL);
    // 3) chunked SSD scan (dt softplus fused into chunk_front)
    chunk_front<<<BATCH * NHEADS * NC, 256, 0, stream>>>(zx, dtb, A_log, pcum, ybuf, Sbuf);
    chunk_state<<<BATCH * NHEADS * 4, 256, 0, stream>>>(Sbuf, pcum);
    chunk_back<<<BATCH * NHEADS * NC, 256, 0, stream>>>(zx, Sbuf, pcum, Dp, ybuf);
    // 4) gate + RMSNorm -> yf (bf16)
    gate_kernel<<<ROWS, 256, 0, stream>>>(ybuf, zx, nw, yf);
    // 5) fc1 GEMM + gelu -> gelu (bf16, aliases zx)
    gemm_p<1><<<32 * 32, 512, 0, stream>>>(
        h_bf, wbf1, ROWS, INTER, DMODEL, 32, nullptr, gelu, fc1_b, nullptr, nullptr,
        nullptr, nullptr, DMODEL);
    // 6) combined (out_proj + fc2) GEMM over concatenated K = 4096 + 8192:
    //    out = yf @ w_out^T + gelu @ w_fc2^T + fc2_b + residual -> d_out (f32)
    gemm_p<4><<<8 * 32, 512, 0, stream>>>(
        yf, wbo, ROWS, DMODEL, DINNER + INTER, 32, outF, nullptr, fc2_b, nullptr, hid,
        gelu, wbf2, DINNER);
}

// Round 13
// 761.361 us; speedup vs baseline: 1.1379x; 1.0198x over previous
//
#include <hip/hip_runtime.h>
#include <hip/hip_bf16.h>

#define BATCH 2
#define SEQ   2048
#define DMODEL 2048
#define DINNER 4096
#define DXB   1024
#define NHEADS 64
#define NKV   16
#define HEADDIM 64
#define DSTATE 64
#define INTER 8192
#define DINPROJ 10304   // 4096 z + 1024 x + 1024 B + 4096 C + 64 dt
#define ROWS  (BATCH*SEQ)   // 4096
#define NC    32            // chunks per sequence
#define EPSV  1e-5f
#define TSTR  72            // padded LDS row stride (144B, 16B-aligned, conflict-free)

typedef short short8 __attribute__((ext_vector_type(8)));
typedef float f32x4 __attribute__((ext_vector_type(4)));

typedef const __attribute__((address_space(1))) unsigned int cg_u32;
typedef __attribute__((address_space(3))) unsigned int ls_u32;

static __device__ __forceinline__ void gll16(const void* g, void* l) {
    __builtin_amdgcn_global_load_lds((cg_u32*)g, (ls_u32*)l, 16, 0, 0);
}

static __device__ __forceinline__ unsigned short f2bf(float f) {
    unsigned int u = __float_as_uint(f);
    unsigned int r = (u + 0x7fffu + ((u >> 16) & 1u)) >> 16;
    return (unsigned short)r;
}
static __device__ __forceinline__ float bf2f(unsigned short h) {
    return __uint_as_float(((unsigned int)h) << 16);
}

// ---------------- all-weights f32 -> bf16 conversion, one dispatch ----------------
__global__ __launch_bounds__(256) void conv4(const float* __restrict__ s0, unsigned short* __restrict__ d0, int n0,
                                             const float* __restrict__ s1, unsigned short* __restrict__ d1, int n1,
                                             const float* __restrict__ s2, unsigned short* __restrict__ d2, int n2,
                                             const float* __restrict__ s3, unsigned short* __restrict__ d3, int n3) {
    int gtid = blockIdx.x * 256 + threadIdx.x;
    int gstr = gridDim.x * 256;
    #define CSEG(S, D, N)                                         \
    for (int i = gtid; i < (N); i += gstr) {                      \
        float4 v = ((const float4*)(S))[i];                       \
        ushort4 o;                                                \
        o.x = f2bf(v.x); o.y = f2bf(v.y);                         \
        o.z = f2bf(v.z); o.w = f2bf(v.w);                         \
        ((ushort4*)(D))[i] = o;                                   \
    }
    CSEG(s0, d0, n0)
    CSEG(s1, d1, n1)
    CSEG(s2, d2, n2)
    CSEG(s3, d3, n3)
    #undef CSEG
}

// ---------------- LayerNorm: one block per row, writes bf16 h ----------------
__global__ __launch_bounds__(256) void ln_kernel(const float* __restrict__ x,
                                                 const float* __restrict__ w,
                                                 const float* __restrict__ b,
                                                 unsigned short* __restrict__ hout) {
    int row = blockIdx.x;
    int t = threadIdx.x;
    const float* xr = x + (size_t)row * DMODEL;
    float v[8];
    float4 v0 = *(const float4*)&xr[t * 8];
    float4 v1 = *(const float4*)&xr[t * 8 + 4];
    v[0]=v0.x; v[1]=v0.y; v[2]=v0.z; v[3]=v0.w; v[4]=v1.x; v[5]=v1.y; v[6]=v1.z; v[7]=v1.w;
    float s = 0.f, s2 = 0.f;
    #pragma unroll
    for (int i = 0; i < 8; ++i) { s += v[i]; s2 += v[i]*v[i]; }
    #pragma unroll
    for (int off = 1; off < 64; off <<= 1) { s += __shfl_xor(s, off); s2 += __shfl_xor(s2, off); }
    __shared__ float sa[4], sb[4];
    int lane = t & 63, wv = t >> 6;
    if (lane == 0) { sa[wv] = s; sb[wv] = s2; }
    __syncthreads();
    s = sa[0]+sa[1]+sa[2]+sa[3];
    s2 = sb[0]+sb[1]+sb[2]+sb[3];
    float mu = s / DMODEL;
    float var = s2 / DMODEL - mu * mu;
    float sc = rsqrtf(var + EPSV);
    unsigned short* ho = hout + (size_t)row * DMODEL + t * 8;
    #pragma unroll
    for (int i = 0; i < 8; ++i) {
        int d = t * 8 + i;
        ho[i] = f2bf((v[i] - mu) * sc * w[d] + b[d]);
    }
}

// ---------------- pipelined bf16 MFMA GEMM: C[M,N] = A[M,K] * B[N,K]^T ----------
// R5/R8 best-known skeleton: 128x256 tile, BK=64, 8 waves (2x4), ring-3 LDS
// (144KB), global_load_lds staging with pre-swizzled source (T2), counted
// vmcnt(6) + 1 barrier per K-tile (T4), setprio (T5), by-fast XCD swizzle (T1).
// Compute: mfma_f32_16x16x32_bf16 (4x4 frags, verified 0 LDS conflicts).
// Dual-source K: segment 1 = (A,B) stride K1, segment 2 = (A2,B2) stride K-K1.
// EPI 0: f32. EPI 1: gelu(acc+bias)->bf16. EPI 2: acc+bias+add1+add2->f32.
// EPI 3: bf16. EPI 4: acc+bias+add2->f32.
#define SLOTSZ 49152
template <int EPI>
__global__ __launch_bounds__(512, 2) void gemm_p(
    const unsigned short* __restrict__ A, const unsigned short* __restrict__ B,
    int M, int N, int K, int nby,
    float* __restrict__ outF, unsigned short* __restrict__ outH,
    const float* __restrict__ bias, const float* __restrict__ add1,
    const float* __restrict__ add2,
    const unsigned short* __restrict__ A2, const unsigned short* __restrict__ B2,
    int K1) {
    __shared__ __align__(16) char smem[3 * SLOTSZ];
    int t = threadIdx.x, lane = t & 63, w = t >> 6;
    int nwg = gridDim.x, cpx = nwg >> 3;
    int logical = (blockIdx.x & 7) * cpx + (blockIdx.x >> 3);
    int by = logical % nby, bx = logical / nby;   // by-fast: B-tile reuse in L2
    int brow = by * 128, bcol = bx * 256;
    int wr = w >> 2, wc = w & 3;
    int wrb = wr * 64, wcb = wc * 64;

    // staging source (swizzled): lane l fetches row (l>>3), chunk (l&7)^(l>>3)
    int lr8 = lane >> 3;
    int lch = ((lane & 7) ^ lr8) << 3;          // element offset within 64-elem row
    const unsigned short* pa[2];
    #pragma unroll
    for (int j = 0; j < 2; ++j)
        pa[j] = A + (size_t)(brow + w * 16 + j * 8 + lr8) * K1 + lch;
    const unsigned short* pb[4];
    #pragma unroll
    for (int j = 0; j < 4; ++j) {
        int r = bcol + w * 32 + j * 8 + lr8;
        if (r > N - 1) r = N - 1;
        pb[j] = B + (size_t)r * K1 + lch;
    }
    auto stageA = [&](int slot, int j) {
        gll16(pa[j], smem + slot * SLOTSZ + (w * 16 + j * 8) * 128);
        pa[j] += 64;
    };
    auto stageB = [&](int slot, int j) {
        gll16(pb[j], smem + slot * SLOTSZ + 16384 + (w * 32 + j * 8) * 128);
        pb[j] += 64;
    };

    // fragment-read swizzle: byte = row*128 + ((c ^ (row&7))*16), c = ks*4 + (lane>>4)
    int arow = lane & 15;
    int swz0 = (((lane >> 4) ^ (lane & 7)) << 4);

    f32x4 acc[4][4] = {};
    const int NT = K >> 6;
    const int KS = K1 >> 6;      // tile index where segment 2 begins
    #pragma unroll
    for (int j = 0; j < 2; ++j) stageA(0, j);
    #pragma unroll
    for (int j = 0; j < 4; ++j) stageB(0, j);
    #pragma unroll
    for (int j = 0; j < 2; ++j) stageA(1, j);
    #pragma unroll
    for (int j = 0; j < 4; ++j) stageB(1, j);

    int slot = 0, slot2 = 2;
    for (int kt = 0; kt < NT; ++kt) {
        if (kt + 1 < NT) { asm volatile("s_waitcnt vmcnt(6)" ::: "memory"); }
        else             { asm volatile("s_waitcnt vmcnt(0)" ::: "memory"); }
        __builtin_amdgcn_s_barrier();
        asm volatile("" ::: "memory");
        const char* Ab = smem + slot * SLOTSZ;
        const char* Bb = Ab + 16384;
        bool st = (kt + 2 < NT);
        // rebase staging pointers at the K-segment boundary (uniform branch)
        if (B2 != nullptr && kt + 2 == KS) {
            int ld2 = K - K1;
            #pragma unroll
            for (int j = 0; j < 2; ++j)
                pa[j] = A2 + (size_t)(brow + w * 16 + j * 8 + lr8) * ld2 + lch;
            #pragma unroll
            for (int j = 0; j < 4; ++j) {
                int r = bcol + w * 32 + j * 8 + lr8;
                if (r > N - 1) r = N - 1;
                pb[j] = B2 + (size_t)r * ld2 + lch;
            }
        }
        // ---- phase 0 (k 0..31) ----
        short8 af[4], bfv[4];
        #pragma unroll
        for (int f = 0; f < 4; ++f)
            af[f] = *(const short8*)(Ab + (wrb + f * 16 + arow) * 128 + swz0);
        #pragma unroll
        for (int n = 0; n < 4; ++n)
            bfv[n] = *(const short8*)(Bb + (wcb + n * 16 + arow) * 128 + swz0);
        if (st) { stageA(slot2, 0); stageA(slot2, 1); stageB(slot2, 0); }
        __builtin_amdgcn_s_setprio(1);
        #pragma unroll
        for (int f = 0; f < 4; ++f)
            #pragma unroll
            for (int n = 0; n < 4; ++n)
                acc[f][n] = __builtin_amdgcn_mfma_f32_16x16x32_bf16(af[f], bfv[n], acc[f][n], 0, 0, 0);
        __builtin_amdgcn_s_setprio(0);
        // ---- phase 1 (k 32..63) ----
        #pragma unroll
        for (int f = 0; f < 4; ++f)
            af[f] = *(const short8*)(Ab + (wrb + f * 16 + arow) * 128 + (swz0 ^ 64));
        #pragma unroll
        for (int n = 0; n < 4; ++n)
            bfv[n] = *(const short8*)(Bb + (wcb + n * 16 + arow) * 128 + (swz0 ^ 64));
        if (st) { stageB(slot2, 1); stageB(slot2, 2); stageB(slot2, 3); }
        __builtin_amdgcn_s_setprio(1);
        #pragma unroll
        for (int f = 0; f < 4; ++f)
            #pragma unroll
            for (int n = 0; n < 4; ++n)
                acc[f][n] = __builtin_amdgcn_mfma_f32_16x16x32_bf16(af[f], bfv[n], acc[f][n], 0, 0, 0);
        __builtin_amdgcn_s_setprio(0);
        slot  = (slot  == 2) ? 0 : slot + 1;
        slot2 = (slot2 == 2) ? 0 : slot2 + 1;
    }

    int rlane = (lane >> 4) << 2, clane = lane & 15;
    #pragma unroll
    for (int f = 0; f < 4; ++f) {
        #pragma unroll
        for (int n = 0; n < 4; ++n) {
            int col = bcol + wcb + n * 16 + clane;
            if (col < N) {
                #pragma unroll
                for (int j = 0; j < 4; ++j) {
                    int row = brow + wrb + f * 16 + rlane + j;
                    size_t idx = (size_t)row * N + col;
                    float v = acc[f][n][j];
                    if constexpr (EPI == 0) {
                        outF[idx] = v;
                    } else if constexpr (EPI == 1) {
                        v += bias[col];
                        float g = 0.5f * v * (1.f + tanhf(0.7978845608f * (v + 0.044715f * v * v * v)));
                        outH[idx] = f2bf(g);
                    } else if constexpr (EPI == 2) {
                        outF[idx] = v + bias[col] + add1[idx] + add2[idx];
                    } else if constexpr (EPI == 4) {
                        outF[idx] = v + bias[col] + add2[idx];
                    } else {
                        outH[idx] = f2bf(v);
                    }
                }
            }
        }
    }
}

// 64x64x64 bf16 MFMA on TSTR-padded LDS tiles: out rows = rows of Al,
// out cols = rows of Bl, K = inner 64. 144B rows -> conflict-free reads.
static __device__ __forceinline__ void mm64(const unsigned short* Al, const unsigned short* Bl,
                                            f32x4* acc, int w, int lane) {
    int lr = lane & 15, kg = (lane >> 4) << 3;
    #pragma unroll
    for (int ks = 0; ks < 2; ++ks) {
        short8 a = *(const short8*)&Al[(w * 16 + lr) * TSTR + ks * 32 + kg];
        #pragma unroll
        for (int fn = 0; fn < 4; ++fn) {
            short8 bb = *(const short8*)&Bl[(fn * 16 + lr) * TSTR + ks * 32 + kg];
            acc[fn] = __builtin_amdgcn_mfma_f32_16x16x32_bf16(a, bb, acc[fn], 0, 0, 0);
        }
    }
}

// ---------------- K1: per-(b,h,chunk) intra-chunk work (dt fused) ----------------
__global__ __launch_bounds__(256) void chunk_front(const unsigned short* __restrict__ zx,
                                                   const float* __restrict__ dt_bias,
                                                   const float* __restrict__ A_log,
                                                   float* __restrict__ pcum,
                                                   unsigned short* __restrict__ ybuf,
                                                   unsigned short* __restrict__ Sbuf) {
    __shared__ __align__(16) unsigned short Cs[64*TSTR], Bsr[64*TSTR], Btr[64*TSTR],
                                            Xtr[64*TSTR], Xw[64*TSTR], Wsm[64*TSTR];
    __shared__ float dts[64], clg[64];
    int t = threadIdx.x, lane = t & 63, w = t >> 6;
    int bid = blockIdx.x;
    int c = bid & 31, h = (bid >> 5) & 63, b = bid >> 11, g = h >> 2;
    int row0 = (b << 11) + (c << 6);

    if (t < 64) {
        float raw = bf2f(zx[(size_t)(row0 + t) * DINPROJ + 10240 + h]) + dt_bias[h];
        float dt = raw > 20.f ? raw : log1pf(expf(raw));
        dts[t] = dt;
        float v = dt * (-expf(A_log[h]));
        #pragma unroll
        for (int off = 1; off < 64; off <<= 1) {
            float o = __shfl_up(v, off);
            if (lane >= off) v += o;
        }
        clg[t] = v;
        pcum[(size_t)(row0 + t) * 64 + h] = expf(v);
    }
    ushort4 xr[4];
    #pragma unroll
    for (int i = 0; i < 4; ++i) {
        int q = i * 256 + t, s = q >> 4, d4 = (q & 15) << 2;
        const unsigned short* rp = zx + (size_t)(row0 + s) * DINPROJ;
        ushort4 cv = *(const ushort4*)&rp[6144 + h * 64 + d4];
        *(ushort4*)&Cs[s * TSTR + d4] = cv;
        ushort4 bv = *(const ushort4*)&rp[5120 + g * 64 + d4];
        *(ushort4*)&Bsr[s * TSTR + d4] = bv;
        Btr[(d4 + 0) * TSTR + s] = bv.x; Btr[(d4 + 1) * TSTR + s] = bv.y;
        Btr[(d4 + 2) * TSTR + s] = bv.z; Btr[(d4 + 3) * TSTR + s] = bv.w;
        ushort4 xv = *(const ushort4*)&rp[4096 + g * 64 + d4];
        Xtr[(d4 + 0) * TSTR + s] = xv.x; Xtr[(d4 + 1) * TSTR + s] = xv.y;
        Xtr[(d4 + 2) * TSTR + s] = xv.z; Xtr[(d4 + 3) * TSTR + s] = xv.w;
        xr[i] = xv;
    }
    __syncthreads();
    float cl63 = clg[63];
    #pragma unroll
    for (int i = 0; i < 4; ++i) {
        int q = i * 256 + t, s = q >> 4, d4 = (q & 15) << 2;
        float ws = dts[s] * expf(cl63 - clg[s]);
        Xw[(d4 + 0) * TSTR + s] = f2bf(bf2f(xr[i].x) * ws);
        Xw[(d4 + 1) * TSTR + s] = f2bf(bf2f(xr[i].y) * ws);
        Xw[(d4 + 2) * TSTR + s] = f2bf(bf2f(xr[i].z) * ws);
        Xw[(d4 + 3) * TSTR + s] = f2bf(bf2f(xr[i].w) * ws);
    }
    __syncthreads();
    f32x4 accG[4] = {};
    mm64(Cs, Bsr, accG, w, lane);
    int rl = (lane >> 4) << 2, cl = lane & 15;
    #pragma unroll
    for (int fn = 0; fn < 4; ++fn) {
        #pragma unroll
        for (int j = 0; j < 4; ++j) {
            int tr = w * 16 + rl + j, rc = fn * 16 + cl;
            float val = 0.f;
            if (rc <= tr) val = accG[fn][j] * expf(clg[tr] - clg[rc]) * dts[rc];
            Wsm[tr * TSTR + rc] = f2bf(val);
        }
    }
    __syncthreads();
    f32x4 accY[4] = {};
    mm64(Wsm, Xtr, accY, w, lane);
    f32x4 accS[4] = {};
    mm64(Xw, Btr, accS, w, lane);
    size_t cb = (size_t)((((b << 6) + h) << 5) + c) * 4096;
    #pragma unroll
    for (int fn = 0; fn < 4; ++fn) {
        #pragma unroll
        for (int j = 0; j < 4; ++j) {
            int tr = w * 16 + rl + j, pc = fn * 16 + cl;
            ybuf[(size_t)(row0 + tr) * DINNER + h * 64 + pc] = f2bf(accY[fn][j]);
            Sbuf[cb + tr * 64 + pc] = f2bf(accS[fn][j]);
        }
    }
}

// ---------------- K2: inter-chunk state recurrence (in-place S -> H0) ----------------
__global__ __launch_bounds__(256) void chunk_state(unsigned short* __restrict__ SH,
                                                   const float* __restrict__ pcum) {
    int bid = blockIdx.x;            // (b,h,q): q = bid&3
    int q = bid & 3, bh = bid >> 2;
    int b = bh >> 6, h = bh & 63;
    int t = threadIdx.x;
    float H[4];
    #pragma unroll
    for (int j = 0; j < 4; ++j) H[j] = 0.f;
    for (int c = 0; c < NC; ++c) {
        size_t base = (size_t)((((b << 6) + h) << 5) + c) * 4096 + q * 1024;
        float Tc = pcum[(size_t)((b << 11) + (c << 6) + 63) * 64 + h];
        #pragma unroll
        for (int j = 0; j < 4; ++j) {
            int e = j * 256 + t;
            unsigned short sv = SH[base + e];
            SH[base + e] = f2bf(H[j]);
            H[j] = H[j] * Tc + bf2f(sv);
        }
    }
}

// ---------------- K3: y += p_t * (C_t . H0) + Dp * x ----------------
__global__ __launch_bounds__(256) void chunk_back(const unsigned short* __restrict__ zx,
                                                  const unsigned short* __restrict__ SH,
                                                  const float* __restrict__ pcum,
                                                  const float* __restrict__ Dp,
                                                  unsigned short* __restrict__ ybuf) {
    __shared__ __align__(16) unsigned short Cs[64*TSTR], Hs[64*TSTR];
    __shared__ float ps[64];
    int t = threadIdx.x, lane = t & 63, w = t >> 6;
    int bid = blockIdx.x;
    int c = bid & 31, h = (bid >> 5) & 63, b = bid >> 11, g = h >> 2;
    int row0 = (b << 11) + (c << 6);
    size_t cb = (size_t)((((b << 6) + h) << 5) + c) * 4096;
    #pragma unroll
    for (int i = 0; i < 4; ++i) {
        int q = i * 256 + t, s = q >> 4, d4 = (q & 15) << 2;
        *(ushort4*)&Cs[s * TSTR + d4] =
            *(const ushort4*)&zx[(size_t)(row0 + s) * DINPROJ + 6144 + h * 64 + d4];
        *(ushort4*)&Hs[s * TSTR + d4] = *(const ushort4*)&SH[cb + s * 64 + d4];
    }
    if (t < 64) ps[t] = pcum[(size_t)(row0 + t) * 64 + h];
    __syncthreads();
    f32x4 acc[4] = {};
    mm64(Cs, Hs, acc, w, lane);
    float Dph = Dp[h];
    int rl = (lane >> 4) << 2, cl = lane & 15;
    #pragma unroll
    for (int fn = 0; fn < 4; ++fn) {
        #pragma unroll
        for (int j = 0; j < 4; ++j) {
            int tr = w * 16 + rl + j, pc = fn * 16 + cl;
            size_t yi = (size_t)(row0 + tr) * DINNER + h * 64 + pc;
            float xv = bf2f(zx[(size_t)(row0 + tr) * DINPROJ + 4096 + g * 64 + pc]);
            ybuf[yi] = f2bf(bf2f(ybuf[yi]) + acc[fn][j] * ps[tr] + Dph * xv);
        }
    }
}

// ---------------- gate (silu) + RMSNorm -> bf16 yf ----------------
__global__ __launch_bounds__(256) void gate_kernel(const unsigned short* __restrict__ y,
                                                   const unsigned short* __restrict__ zx,
                                                   const float* __restrict__ norm_w,
                                                   unsigned short* __restrict__ yf) {
    int row = blockIdx.x;
    int t = threadIdx.x;
    float v[16];
    float s2 = 0.f;
    #pragma unroll
    for (int i = 0; i < 16; ++i) {
        int d = i * 256 + t;
        float yv = bf2f(y[(size_t)row * DINNER + d]);
        float zv = bf2f(zx[(size_t)row * DINPROJ + d]);
        float gt = zv / (1.f + expf(-zv));
        v[i] = yv * gt;
        s2 += v[i] * v[i];
    }
    #pragma unroll
    for (int off = 1; off < 64; off <<= 1) s2 += __shfl_xor(s2, off);
    __shared__ float sb[4];
    int lane = t & 63, wv = t >> 6;
    if (lane == 0) sb[wv] = s2;
    __syncthreads();
    s2 = sb[0] + sb[1] + sb[2] + sb[3];
    float sc = rsqrtf(s2 / DINNER + EPSV);
    #pragma unroll
    for (int i = 0; i < 16; ++i) {
        int d = i * 256 + t;
        yf[(size_t)row * DINNER + d] = f2bf(v[i] * sc * norm_w[d]);
    }
}

extern "C" void kernel_launch(void* const* d_in, const int* in_sizes, int n_in,
                              void* d_out, int out_size, void* d_ws, size_t ws_size,
                              hipStream_t stream) {
    const float* hid   = (const float*)d_in[0];
    const float* ln_w  = (const float*)d_in[1];
    const float* ln_b  = (const float*)d_in[2];
    const float* w_inp = (const float*)d_in[3];
    const float* dtb   = (const float*)d_in[4];
    const float* A_log = (const float*)d_in[5];
    const float* Dp    = (const float*)d_in[6];
    const float* nw    = (const float*)d_in[7];
    const float* w_out = (const float*)d_in[8];
    const float* w_fc1 = (const float*)d_in[9];
    const float* fc1_b = (const float*)d_in[10];
    const float* w_fc2 = (const float*)d_in[11];
    const float* fc2_b = (const float*)d_in[12];

    char* ws = (char*)d_ws;
    size_t off = 0;
    auto alloc = [&](size_t bytes) { size_t o = off; off += (bytes + 255) & ~(size_t)255; return o; };
    size_t o_h    = alloc((size_t)ROWS * DMODEL * 2);        // h bf16
    size_t o_wi   = alloc((size_t)DINPROJ * DMODEL * 2);     // w_inp bf16
    size_t o_wo   = alloc((size_t)DMODEL * DINNER * 2);      // w_out bf16
    size_t o_wf1  = alloc((size_t)INTER * DMODEL * 2);       // w_fc1 bf16
    size_t o_wf2  = alloc((size_t)DMODEL * INTER * 2);       // w_fc2 bf16
    size_t o_zx   = alloc((size_t)ROWS * DINPROJ * 2);       // zxbcdt bf16 (later: gelu bf16)
    size_t o_pc   = alloc((size_t)ROWS * NHEADS * 4);        // pcum f32
    size_t o_y    = alloc((size_t)ROWS * DINNER * 2);        // y bf16
    size_t o_yf   = alloc((size_t)ROWS * DINNER * 2);        // yf bf16
    size_t o_S    = alloc((size_t)BATCH * NHEADS * NC * HEADDIM * DSTATE * 2); // S->H0 bf16

    unsigned short* h_bf  = (unsigned short*)(ws + o_h);
    unsigned short* wbi   = (unsigned short*)(ws + o_wi);
    unsigned short* wbo   = (unsigned short*)(ws + o_wo);
    unsigned short* wbf1  = (unsigned short*)(ws + o_wf1);
    unsigned short* wbf2  = (unsigned short*)(ws + o_wf2);
    unsigned short* zx    = (unsigned short*)(ws + o_zx);
    float* pcum           = (float*)(ws + o_pc);
    unsigned short* ybuf  = (unsigned short*)(ws + o_y);
    unsigned short* yf    = (unsigned short*)(ws + o_yf);
    unsigned short* Sbuf  = (unsigned short*)(ws + o_S);
    unsigned short* gelu  = (unsigned short*)(ws + o_zx);    // alias: zx dead after gate
    float* outF           = (float*)d_out;

    // 0) all weight conversions in one dispatch
    conv4<<<2048, 256, 0, stream>>>(
        w_inp, wbi,  (DINPROJ * DMODEL) / 4,
        w_out, wbo,  (DMODEL * DINNER) / 4,
        w_fc1, wbf1, (INTER * DMODEL) / 4,
        w_fc2, wbf2, (DMODEL * INTER) / 4);
    // 1) LayerNorm -> h (bf16)
    ln_kernel<<<ROWS, 256, 0, stream>>>(hid, ln_w, ln_b, h_bf);
    // 2) in_proj GEMM -> zx (bf16); grid = 41 col-tiles x 32 row-tiles
    gemm_p<3><<<41 * 32, 512, 0, stream>>>(
        h_bf, wbi, ROWS, DINPROJ, DMODEL, 32, nullptr, zx, nullptr, nullptr, nullptr,
        nullptr, nullptr, DMODEL);
    // 3) chunked SSD scan (dt softplus fused into chunk_front)
    chunk_front<<<BATCH * NHEADS * NC, 256, 0, stream>>>(zx, dtb, A_log, pcum, ybuf, Sbuf);
    chunk_state<<<BATCH * NHEADS * 4, 256, 0, stream>>>(Sbuf, pcum);
    chunk_back<<<BATCH * NHEADS * NC, 256, 0, stream>>>(zx, Sbuf, pcum, Dp, ybuf);
    // 4) gate + RMSNorm -> yf (bf16)
    gate_kernel<<<ROWS, 256, 0, stream>>>(ybuf, zx, nw, yf);
    // 5) fc1 GEMM + gelu -> gelu (bf16, aliases zx)
    gemm_p<1><<<32 * 32, 512, 0, stream>>>(
        h_bf, wbf1, ROWS, INTER, DMODEL, 32, nullptr, gelu, fc1_b, nullptr, nullptr,
        nullptr, nullptr, DMODEL);
    // 6) combined (out_proj + fc2) GEMM over concatenated K = 4096 + 8192:
    //    out = yf @ w_out^T + gelu @ w_fc2^T + fc2_b + residual -> d_out (f32)
    gemm_p<4><<<8 * 32, 512, 0, stream>>>(
        yf, wbo, ROWS, DMODEL, DINNER + INTER, 32, outF, nullptr, fc2_b, nullptr, hid,
        gelu, wbf2, DINNER);
}

// Round 14
// 748.080 us; speedup vs baseline: 1.1581x; 1.0178x over previous
//
#include <hip/hip_runtime.h>
#include <hip/hip_bf16.h>

#define BATCH 2
#define SEQ   2048
#define DMODEL 2048
#define DINNER 4096
#define DXB   1024
#define NHEADS 64
#define NKV   16
#define HEADDIM 64
#define DSTATE 64
#define INTER 8192
#define DINPROJ 10304   // 4096 z + 1024 x + 1024 B + 4096 C + 64 dt
#define ROWS  (BATCH*SEQ)   // 4096
#define NC    32            // chunks per sequence
#define EPSV  1e-5f
#define TSTR  72            // padded LDS row stride for scan kernels

typedef short short8 __attribute__((ext_vector_type(8)));
typedef float f32x4 __attribute__((ext_vector_type(4)));

typedef const __attribute__((address_space(1))) unsigned int cg_u32;
typedef __attribute__((address_space(3))) unsigned int ls_u32;

static __device__ __forceinline__ void gll16(const void* g, void* l) {
    __builtin_amdgcn_global_load_lds((cg_u32*)g, (ls_u32*)l, 16, 0, 0);
}

static __device__ __forceinline__ unsigned short f2bf(float f) {
    unsigned int u = __float_as_uint(f);
    unsigned int r = (u + 0x7fffu + ((u >> 16) & 1u)) >> 16;
    return (unsigned short)r;
}
static __device__ __forceinline__ float bf2f(unsigned short h) {
    return __uint_as_float(((unsigned int)h) << 16);
}

// ---------------- all-weights f32 -> bf16 conversion, one dispatch ----------------
__global__ __launch_bounds__(256) void conv4(const float* __restrict__ s0, unsigned short* __restrict__ d0, int n0,
                                             const float* __restrict__ s1, unsigned short* __restrict__ d1, int n1,
                                             const float* __restrict__ s2, unsigned short* __restrict__ d2, int n2,
                                             const float* __restrict__ s3, unsigned short* __restrict__ d3, int n3) {
    int gtid = blockIdx.x * 256 + threadIdx.x;
    int gstr = gridDim.x * 256;
    #define CSEG(S, D, N)                                         \
    for (int i = gtid; i < (N); i += gstr) {                      \
        float4 v = ((const float4*)(S))[i];                       \
        ushort4 o;                                                \
        o.x = f2bf(v.x); o.y = f2bf(v.y);                         \
        o.z = f2bf(v.z); o.w = f2bf(v.w);                         \
        ((ushort4*)(D))[i] = o;                                   \
    }
    CSEG(s0, d0, n0)
    CSEG(s1, d1, n1)
    CSEG(s2, d2, n2)
    CSEG(s3, d3, n3)
    #undef CSEG
}

// ---------------- LayerNorm: one block per row, writes bf16 h ----------------
__global__ __launch_bounds__(256) void ln_kernel(const float* __restrict__ x,
                                                 const float* __restrict__ w,
                                                 const float* __restrict__ b,
                                                 unsigned short* __restrict__ hout) {
    int row = blockIdx.x;
    int t = threadIdx.x;
    const float* xr = x + (size_t)row * DMODEL;
    float v[8];
    float4 v0 = *(const float4*)&xr[t * 8];
    float4 v1 = *(const float4*)&xr[t * 8 + 4];
    v[0]=v0.x; v[1]=v0.y; v[2]=v0.z; v[3]=v0.w; v[4]=v1.x; v[5]=v1.y; v[6]=v1.z; v[7]=v1.w;
    float s = 0.f, s2 = 0.f;
    #pragma unroll
    for (int i = 0; i < 8; ++i) { s += v[i]; s2 += v[i]*v[i]; }
    #pragma unroll
    for (int off = 1; off < 64; off <<= 1) { s += __shfl_xor(s, off); s2 += __shfl_xor(s2, off); }
    __shared__ float sa[4], sb[4];
    int lane = t & 63, wv = t >> 6;
    if (lane == 0) { sa[wv] = s; sb[wv] = s2; }
    __syncthreads();
    s = sa[0]+sa[1]+sa[2]+sa[3];
    s2 = sb[0]+sb[1]+sb[2]+sb[3];
    float mu = s / DMODEL;
    float var = s2 / DMODEL - mu * mu;
    float sc = rsqrtf(var + EPSV);
    unsigned short* ho = hout + (size_t)row * DMODEL + t * 8;
    #pragma unroll
    for (int i = 0; i < 8; ++i) {
        int d = t * 8 + i;
        ho[i] = f2bf((v[i] - mu) * sc * w[d] + b[d]);
    }
}

// ========== gemm_q: 256x256 tile, BK=32, ring-4 LDS (128KB), loose rhythm =========
// 8 waves (2M x 4N), wave tile 128x64 (8x4 frags of 16x16x32). Per K-tile:
// counted vmcnt(8) (never drains; 3-tile issue-to-use distance) + 1 barrier,
// 12 ds_read_b128 + 4 gll16 stage + 32 MFMA (setprio-wrapped).
// Swizzle (both-sides involution, 64B rows of 4x16B chunks): chunk ^= (row>>1)&3.
// Wave-read = exactly 8 words/bank (minimal). EPI 1: gelu->bf16. EPI 3: bf16.
#define QSLOT 32768
template <int EPI>
__global__ __launch_bounds__(512, 1) void gemm_q(
    const unsigned short* __restrict__ A, const unsigned short* __restrict__ B,
    int M, int N, int K, int nby,
    float* __restrict__ outF, unsigned short* __restrict__ outH,
    const float* __restrict__ bias) {
    __shared__ __align__(16) char smem[4 * QSLOT];
    int t = threadIdx.x, lane = t & 63, w = t >> 6;
    int nwg = gridDim.x, cpx = nwg >> 3;
    int logical = (blockIdx.x & 7) * cpx + (blockIdx.x >> 3);
    int by = logical % nby, bx = logical / nby;   // by-fast: B-tile reuse in L2
    int brow = by * 256, bcol = bx * 256;
    int wm = w >> 2, wn = w & 3;
    int wrb = wm * 128, wcb = wn * 64;

    // staging: lane covers row lane>>2, chunk-slot lane&3; source chunk pre-swizzled
    int lrow4 = lane >> 2;
    int scs = ((lane & 3) ^ ((lane >> 3) & 3)) << 3;   // element offset in 32-elem row
    const unsigned short* pa[2];
    #pragma unroll
    for (int j = 0; j < 2; ++j)
        pa[j] = A + (size_t)(brow + w * 32 + j * 16 + lrow4) * K + scs;
    const unsigned short* pb[2];
    #pragma unroll
    for (int j = 0; j < 2; ++j) {
        int r = bcol + w * 32 + j * 16 + lrow4;
        if (r > N - 1) r = N - 1;
        pb[j] = B + (size_t)r * K + scs;
    }
    auto stage = [&](int kt) {
        int slot = kt & 3;
        #pragma unroll
        for (int j = 0; j < 2; ++j) {
            gll16(pa[j], smem + slot * QSLOT + (w * 32 + j * 16) * 64);
            pa[j] += 32;
        }
        #pragma unroll
        for (int j = 0; j < 2; ++j) {
            gll16(pb[j], smem + slot * QSLOT + 16384 + (w * 32 + j * 16) * 64);
            pb[j] += 32;
        }
    };

    // fragment-read: row r, logical chunk kq = lane>>4; slot = kq ^ ((arow>>1)&3)
    int arow = lane & 15;
    int rsw = ((lane >> 4) ^ ((arow >> 1) & 3)) << 4;  // byte offset of chunk in row

    f32x4 acc[8][4] = {};
    const int NT = K >> 5;
    stage(0); stage(1); stage(2);

    for (int kt = 0; kt < NT; ++kt) {
        if (kt + 2 < NT)      { asm volatile("s_waitcnt vmcnt(8)" ::: "memory"); }
        else if (kt + 1 < NT) { asm volatile("s_waitcnt vmcnt(4)" ::: "memory"); }
        else                  { asm volatile("s_waitcnt vmcnt(0)" ::: "memory"); }
        __builtin_amdgcn_s_barrier();
        asm volatile("" ::: "memory");
        const char* Ab = smem + (kt & 3) * QSLOT;
        const char* Bb = Ab + 16384;
        short8 af[8], bfv[4];
        #pragma unroll
        for (int f = 0; f < 8; ++f) {
            int r = wrb + f * 16 + arow;
            af[f] = *(const short8*)(Ab + r * 64 + rsw);
        }
        #pragma unroll
        for (int n = 0; n < 4; ++n) {
            int r = wcb + n * 16 + arow;
            bfv[n] = *(const short8*)(Bb + r * 64 + rsw);
        }
        if (kt + 3 < NT) stage(kt + 3);
        __builtin_amdgcn_s_setprio(1);
        #pragma unroll
        for (int f = 0; f < 8; ++f)
            #pragma unroll
            for (int n = 0; n < 4; ++n)
                acc[f][n] = __builtin_amdgcn_mfma_f32_16x16x32_bf16(af[f], bfv[n], acc[f][n], 0, 0, 0);
        __builtin_amdgcn_s_setprio(0);
    }

    int rlane = (lane >> 4) << 2, clane = lane & 15;
    #pragma unroll
    for (int f = 0; f < 8; ++f) {
        #pragma unroll
        for (int n = 0; n < 4; ++n) {
            int col = bcol + wcb + n * 16 + clane;
            if (col < N) {
                #pragma unroll
                for (int j = 0; j < 4; ++j) {
                    int row = brow + wrb + f * 16 + rlane + j;
                    size_t idx = (size_t)row * N + col;
                    float v = acc[f][n][j];
                    if constexpr (EPI == 1) {
                        v += bias[col];
                        float g = 0.5f * v * (1.f + tanhf(0.7978845608f * (v + 0.044715f * v * v * v)));
                        outH[idx] = f2bf(g);
                    } else {
                        outH[idx] = f2bf(v);
                    }
                }
            }
        }
    }
}

// ---------------- gemm_p: 128x256 R5 skeleton (kept for the combined GEMM) ------
// Dual-source K: segment 1 = (A,B) stride K1, segment 2 = (A2,B2) stride K-K1.
// EPI 4: acc+bias+add2 -> f32.
#define SLOTSZ 49152
template <int EPI>
__global__ __launch_bounds__(512, 2) void gemm_p(
    const unsigned short* __restrict__ A, const unsigned short* __restrict__ B,
    int M, int N, int K, int nby,
    float* __restrict__ outF, unsigned short* __restrict__ outH,
    const float* __restrict__ bias, const float* __restrict__ add1,
    const float* __restrict__ add2,
    const unsigned short* __restrict__ A2, const unsigned short* __restrict__ B2,
    int K1) {
    __shared__ __align__(16) char smem[3 * SLOTSZ];
    int t = threadIdx.x, lane = t & 63, w = t >> 6;
    int nwg = gridDim.x, cpx = nwg >> 3;
    int logical = (blockIdx.x & 7) * cpx + (blockIdx.x >> 3);
    int by = logical % nby, bx = logical / nby;
    int brow = by * 128, bcol = bx * 256;
    int wr = w >> 2, wc = w & 3;
    int wrb = wr * 64, wcb = wc * 64;

    int lr8 = lane >> 3;
    int lch = ((lane & 7) ^ lr8) << 3;
    const unsigned short* pa[2];
    #pragma unroll
    for (int j = 0; j < 2; ++j)
        pa[j] = A + (size_t)(brow + w * 16 + j * 8 + lr8) * K1 + lch;
    const unsigned short* pb[4];
    #pragma unroll
    for (int j = 0; j < 4; ++j) {
        int r = bcol + w * 32 + j * 8 + lr8;
        if (r > N - 1) r = N - 1;
        pb[j] = B + (size_t)r * K1 + lch;
    }
    auto stageA = [&](int slot, int j) {
        gll16(pa[j], smem + slot * SLOTSZ + (w * 16 + j * 8) * 128);
        pa[j] += 64;
    };
    auto stageB = [&](int slot, int j) {
        gll16(pb[j], smem + slot * SLOTSZ + 16384 + (w * 32 + j * 8) * 128);
        pb[j] += 64;
    };

    int arow = lane & 15;
    int swz0 = (((lane >> 4) ^ (lane & 7)) << 4);

    f32x4 acc[4][4] = {};
    const int NT = K >> 6;
    const int KS = K1 >> 6;
    #pragma unroll
    for (int j = 0; j < 2; ++j) stageA(0, j);
    #pragma unroll
    for (int j = 0; j < 4; ++j) stageB(0, j);
    #pragma unroll
    for (int j = 0; j < 2; ++j) stageA(1, j);
    #pragma unroll
    for (int j = 0; j < 4; ++j) stageB(1, j);

    int slot = 0, slot2 = 2;
    for (int kt = 0; kt < NT; ++kt) {
        if (kt + 1 < NT) { asm volatile("s_waitcnt vmcnt(6)" ::: "memory"); }
        else             { asm volatile("s_waitcnt vmcnt(0)" ::: "memory"); }
        __builtin_amdgcn_s_barrier();
        asm volatile("" ::: "memory");
        const char* Ab = smem + slot * SLOTSZ;
        const char* Bb = Ab + 16384;
        bool st = (kt + 2 < NT);
        if (B2 != nullptr && kt + 2 == KS) {
            int ld2 = K - K1;
            #pragma unroll
            for (int j = 0; j < 2; ++j)
                pa[j] = A2 + (size_t)(brow + w * 16 + j * 8 + lr8) * ld2 + lch;
            #pragma unroll
            for (int j = 0; j < 4; ++j) {
                int r = bcol + w * 32 + j * 8 + lr8;
                if (r > N - 1) r = N - 1;
                pb[j] = B2 + (size_t)r * ld2 + lch;
            }
        }
        short8 af[4], bfv[4];
        #pragma unroll
        for (int f = 0; f < 4; ++f)
            af[f] = *(const short8*)(Ab + (wrb + f * 16 + arow) * 128 + swz0);
        #pragma unroll
        for (int n = 0; n < 4; ++n)
            bfv[n] = *(const short8*)(Bb + (wcb + n * 16 + arow) * 128 + swz0);
        if (st) { stageA(slot2, 0); stageA(slot2, 1); stageB(slot2, 0); }
        __builtin_amdgcn_s_setprio(1);
        #pragma unroll
        for (int f = 0; f < 4; ++f)
            #pragma unroll
            for (int n = 0; n < 4; ++n)
                acc[f][n] = __builtin_amdgcn_mfma_f32_16x16x32_bf16(af[f], bfv[n], acc[f][n], 0, 0, 0);
        __builtin_amdgcn_s_setprio(0);
        #pragma unroll
        for (int f = 0; f < 4; ++f)
            af[f] = *(const short8*)(Ab + (wrb + f * 16 + arow) * 128 + (swz0 ^ 64));
        #pragma unroll
        for (int n = 0; n < 4; ++n)
            bfv[n] = *(const short8*)(Bb + (wcb + n * 16 + arow) * 128 + (swz0 ^ 64));
        if (st) { stageB(slot2, 1); stageB(slot2, 2); stageB(slot2, 3); }
        __builtin_amdgcn_s_setprio(1);
        #pragma unroll
        for (int f = 0; f < 4; ++f)
            #pragma unroll
            for (int n = 0; n < 4; ++n)
                acc[f][n] = __builtin_amdgcn_mfma_f32_16x16x32_bf16(af[f], bfv[n], acc[f][n], 0, 0, 0);
        __builtin_amdgcn_s_setprio(0);
        slot  = (slot  == 2) ? 0 : slot + 1;
        slot2 = (slot2 == 2) ? 0 : slot2 + 1;
    }

    int rlane = (lane >> 4) << 2, clane = lane & 15;
    #pragma unroll
    for (int f = 0; f < 4; ++f) {
        #pragma unroll
        for (int n = 0; n < 4; ++n) {
            int col = bcol + wcb + n * 16 + clane;
            if (col < N) {
                #pragma unroll
                for (int j = 0; j < 4; ++j) {
                    int row = brow + wrb + f * 16 + rlane + j;
                    size_t idx = (size_t)row * N + col;
                    float v = acc[f][n][j];
                    if constexpr (EPI == 4) {
                        outF[idx] = v + bias[col] + add2[idx];
                    } else {
                        outF[idx] = v;
                    }
                }
            }
        }
    }
}

// 64x64x64 bf16 MFMA on TSTR-padded LDS tiles.
static __device__ __forceinline__ void mm64(const unsigned short* Al, const unsigned short* Bl,
                                            f32x4* acc, int w, int lane) {
    int lr = lane & 15, kg = (lane >> 4) << 3;
    #pragma unroll
    for (int ks = 0; ks < 2; ++ks) {
        short8 a = *(const short8*)&Al[(w * 16 + lr) * TSTR + ks * 32 + kg];
        #pragma unroll
        for (int fn = 0; fn < 4; ++fn) {
            short8 bb = *(const short8*)&Bl[(fn * 16 + lr) * TSTR + ks * 32 + kg];
            acc[fn] = __builtin_amdgcn_mfma_f32_16x16x32_bf16(a, bb, acc[fn], 0, 0, 0);
        }
    }
}

// ---------------- K1: per-(b,h,chunk) intra-chunk work (dt fused) ----------------
__global__ __launch_bounds__(256) void chunk_front(const unsigned short* __restrict__ zx,
                                                   const float* __restrict__ dt_bias,
                                                   const float* __restrict__ A_log,
                                                   float* __restrict__ pcum,
                                                   unsigned short* __restrict__ ybuf,
                                                   unsigned short* __restrict__ Sbuf) {
    __shared__ __align__(16) unsigned short Cs[64*TSTR], Bsr[64*TSTR], Btr[64*TSTR],
                                            Xtr[64*TSTR], Xw[64*TSTR], Wsm[64*TSTR];
    __shared__ float dts[64], clg[64];
    int t = threadIdx.x, lane = t & 63, w = t >> 6;
    int bid = blockIdx.x;
    int c = bid & 31, h = (bid >> 5) & 63, b = bid >> 11, g = h >> 2;
    int row0 = (b << 11) + (c << 6);

    if (t < 64) {
        float raw = bf2f(zx[(size_t)(row0 + t) * DINPROJ + 10240 + h]) + dt_bias[h];
        float dt = raw > 20.f ? raw : log1pf(expf(raw));
        dts[t] = dt;
        float v = dt * (-expf(A_log[h]));
        #pragma unroll
        for (int off = 1; off < 64; off <<= 1) {
            float o = __shfl_up(v, off);
            if (lane >= off) v += o;
        }
        clg[t] = v;
        pcum[(size_t)(row0 + t) * 64 + h] = expf(v);
    }
    ushort4 xr[4];
    #pragma unroll
    for (int i = 0; i < 4; ++i) {
        int q = i * 256 + t, s = q >> 4, d4 = (q & 15) << 2;
        const unsigned short* rp = zx + (size_t)(row0 + s) * DINPROJ;
        ushort4 cv = *(const ushort4*)&rp[6144 + h * 64 + d4];
        *(ushort4*)&Cs[s * TSTR + d4] = cv;
        ushort4 bv = *(const ushort4*)&rp[5120 + g * 64 + d4];
        *(ushort4*)&Bsr[s * TSTR + d4] = bv;
        Btr[(d4 + 0) * TSTR + s] = bv.x; Btr[(d4 + 1) * TSTR + s] = bv.y;
        Btr[(d4 + 2) * TSTR + s] = bv.z; Btr[(d4 + 3) * TSTR + s] = bv.w;
        ushort4 xv = *(const ushort4*)&rp[4096 + g * 64 + d4];
        Xtr[(d4 + 0) * TSTR + s] = xv.x; Xtr[(d4 + 1) * TSTR + s] = xv.y;
        Xtr[(d4 + 2) * TSTR + s] = xv.z; Xtr[(d4 + 3) * TSTR + s] = xv.w;
        xr[i] = xv;
    }
    __syncthreads();
    float cl63 = clg[63];
    #pragma unroll
    for (int i = 0; i < 4; ++i) {
        int q = i * 256 + t, s = q >> 4, d4 = (q & 15) << 2;
        float ws = dts[s] * expf(cl63 - clg[s]);
        Xw[(d4 + 0) * TSTR + s] = f2bf(bf2f(xr[i].x) * ws);
        Xw[(d4 + 1) * TSTR + s] = f2bf(bf2f(xr[i].y) * ws);
        Xw[(d4 + 2) * TSTR + s] = f2bf(bf2f(xr[i].z) * ws);
        Xw[(d4 + 3) * TSTR + s] = f2bf(bf2f(xr[i].w) * ws);
    }
    __syncthreads();
    f32x4 accG[4] = {};
    mm64(Cs, Bsr, accG, w, lane);
    int rl = (lane >> 4) << 2, cl = lane & 15;
    #pragma unroll
    for (int fn = 0; fn < 4; ++fn) {
        #pragma unroll
        for (int j = 0; j < 4; ++j) {
            int tr = w * 16 + rl + j, rc = fn * 16 + cl;
            float val = 0.f;
            if (rc <= tr) val = accG[fn][j] * expf(clg[tr] - clg[rc]) * dts[rc];
            Wsm[tr * TSTR + rc] = f2bf(val);
        }
    }
    __syncthreads();
    f32x4 accY[4] = {};
    mm64(Wsm, Xtr, accY, w, lane);
    f32x4 accS[4] = {};
    mm64(Xw, Btr, accS, w, lane);
    size_t cb = (size_t)((((b << 6) + h) << 5) + c) * 4096;
    #pragma unroll
    for (int fn = 0; fn < 4; ++fn) {
        #pragma unroll
        for (int j = 0; j < 4; ++j) {
            int tr = w * 16 + rl + j, pc = fn * 16 + cl;
            ybuf[(size_t)(row0 + tr) * DINNER + h * 64 + pc] = f2bf(accY[fn][j]);
            Sbuf[cb + tr * 64 + pc] = f2bf(accS[fn][j]);
        }
    }
}

// ---------------- K2: inter-chunk state recurrence (in-place S -> H0) ----------------
__global__ __launch_bounds__(256) void chunk_state(unsigned short* __restrict__ SH,
                                                   const float* __restrict__ pcum) {
    int bid = blockIdx.x;
    int q = bid & 3, bh = bid >> 2;
    int b = bh >> 6, h = bh & 63;
    int t = threadIdx.x;
    float H[4];
    #pragma unroll
    for (int j = 0; j < 4; ++j) H[j] = 0.f;
    for (int c = 0; c < NC; ++c) {
        size_t base = (size_t)((((b << 6) + h) << 5) + c) * 4096 + q * 1024;
        float Tc = pcum[(size_t)((b << 11) + (c << 6) + 63) * 64 + h];
        #pragma unroll
        for (int j = 0; j < 4; ++j) {
            int e = j * 256 + t;
            unsigned short sv = SH[base + e];
            SH[base + e] = f2bf(H[j]);
            H[j] = H[j] * Tc + bf2f(sv);
        }
    }
}

// ---------------- K3: y += p_t * (C_t . H0) + Dp * x ----------------
__global__ __launch_bounds__(256) void chunk_back(const unsigned short* __restrict__ zx,
                                                  const unsigned short* __restrict__ SH,
                                                  const float* __restrict__ pcum,
                                                  const float* __restrict__ Dp,
                                                  unsigned short* __restrict__ ybuf) {
    __shared__ __align__(16) unsigned short Cs[64*TSTR], Hs[64*TSTR];
    __shared__ float ps[64];
    int t = threadIdx.x, lane = t & 63, w = t >> 6;
    int bid = blockIdx.x;
    int c = bid & 31, h = (bid >> 5) & 63, b = bid >> 11, g = h >> 2;
    int row0 = (b << 11) + (c << 6);
    size_t cb = (size_t)((((b << 6) + h) << 5) + c) * 4096;
    #pragma unroll
    for (int i = 0; i < 4; ++i) {
        int q = i * 256 + t, s = q >> 4, d4 = (q & 15) << 2;
        *(ushort4*)&Cs[s * TSTR + d4] =
            *(const ushort4*)&zx[(size_t)(row0 + s) * DINPROJ + 6144 + h * 64 + d4];
        *(ushort4*)&Hs[s * TSTR + d4] = *(const ushort4*)&SH[cb + s * 64 + d4];
    }
    if (t < 64) ps[t] = pcum[(size_t)(row0 + t) * 64 + h];
    __syncthreads();
    f32x4 acc[4] = {};
    mm64(Cs, Hs, acc, w, lane);
    float Dph = Dp[h];
    int rl = (lane >> 4) << 2, cl = lane & 15;
    #pragma unroll
    for (int fn = 0; fn < 4; ++fn) {
        #pragma unroll
        for (int j = 0; j < 4; ++j) {
            int tr = w * 16 + rl + j, pc = fn * 16 + cl;
            size_t yi = (size_t)(row0 + tr) * DINNER + h * 64 + pc;
            float xv = bf2f(zx[(size_t)(row0 + tr) * DINPROJ + 4096 + g * 64 + pc]);
            ybuf[yi] = f2bf(bf2f(ybuf[yi]) + acc[fn][j] * ps[tr] + Dph * xv);
        }
    }
}

// ---------------- gate (silu) + RMSNorm -> bf16 yf ----------------
__global__ __launch_bounds__(256) void gate_kernel(const unsigned short* __restrict__ y,
                                                   const unsigned short* __restrict__ zx,
                                                   const float* __restrict__ norm_w,
                                                   unsigned short* __restrict__ yf) {
    int row = blockIdx.x;
    int t = threadIdx.x;
    float v[16];
    float s2 = 0.f;
    #pragma unroll
    for (int i = 0; i < 16; ++i) {
        int d = i * 256 + t;
        float yv = bf2f(y[(size_t)row * DINNER + d]);
        float zv = bf2f(zx[(size_t)row * DINPROJ + d]);
        float gt = zv / (1.f + expf(-zv));
        v[i] = yv * gt;
        s2 += v[i] * v[i];
    }
    #pragma unroll
    for (int off = 1; off < 64; off <<= 1) s2 += __shfl_xor(s2, off);
    __shared__ float sb[4];
    int lane = t & 63, wv = t >> 6;
    if (lane == 0) sb[wv] = s2;
    __syncthreads();
    s2 = sb[0] + sb[1] + sb[2] + sb[3];
    float sc = rsqrtf(s2 / DINNER + EPSV);
    #pragma unroll
    for (int i = 0; i < 16; ++i) {
        int d = i * 256 + t;
        yf[(size_t)row * DINNER + d] = f2bf(v[i] * sc * norm_w[d]);
    }
}

extern "C" void kernel_launch(void* const* d_in, const int* in_sizes, int n_in,
                              void* d_out, int out_size, void* d_ws, size_t ws_size,
                              hipStream_t stream) {
    const float* hid   = (const float*)d_in[0];
    const float* ln_w  = (const float*)d_in[1];
    const float* ln_b  = (const float*)d_in[2];
    const float* w_inp = (const float*)d_in[3];
    const float* dtb   = (const float*)d_in[4];
    const float* A_log = (const float*)d_in[5];
    const float* Dp    = (const float*)d_in[6];
    const float* nw    = (const float*)d_in[7];
    const float* w_out = (const float*)d_in[8];
    const float* w_fc1 = (const float*)d_in[9];
    const float* fc1_b = (const float*)d_in[10];
    const float* w_fc2 = (const float*)d_in[11];
    const float* fc2_b = (const float*)d_in[12];

    char* ws = (char*)d_ws;
    size_t off = 0;
    auto alloc = [&](size_t bytes) { size_t o = off; off += (bytes + 255) & ~(size_t)255; return o; };
    size_t o_h    = alloc((size_t)ROWS * DMODEL * 2);
    size_t o_wi   = alloc((size_t)DINPROJ * DMODEL * 2);
    size_t o_wo   = alloc((size_t)DMODEL * DINNER * 2);
    size_t o_wf1  = alloc((size_t)INTER * DMODEL * 2);
    size_t o_wf2  = alloc((size_t)DMODEL * INTER * 2);
    size_t o_zx   = alloc((size_t)ROWS * DINPROJ * 2);
    size_t o_pc   = alloc((size_t)ROWS * NHEADS * 4);
    size_t o_y    = alloc((size_t)ROWS * DINNER * 2);
    size_t o_yf   = alloc((size_t)ROWS * DINNER * 2);
    size_t o_S    = alloc((size_t)BATCH * NHEADS * NC * HEADDIM * DSTATE * 2);

    unsigned short* h_bf  = (unsigned short*)(ws + o_h);
    unsigned short* wbi   = (unsigned short*)(ws + o_wi);
    unsigned short* wbo   = (unsigned short*)(ws + o_wo);
    unsigned short* wbf1  = (unsigned short*)(ws + o_wf1);
    unsigned short* wbf2  = (unsigned short*)(ws + o_wf2);
    unsigned short* zx    = (unsigned short*)(ws + o_zx);
    float* pcum           = (float*)(ws + o_pc);
    unsigned short* ybuf  = (unsigned short*)(ws + o_y);
    unsigned short* yf    = (unsigned short*)(ws + o_yf);
    unsigned short* Sbuf  = (unsigned short*)(ws + o_S);
    unsigned short* gelu  = (unsigned short*)(ws + o_zx);    // alias: zx dead after gate
    float* outF           = (float*)d_out;

    // 0) all weight conversions in one dispatch
    conv4<<<2048, 256, 0, stream>>>(
        w_inp, wbi,  (DINPROJ * DMODEL) / 4,
        w_out, wbo,  (DMODEL * DINNER) / 4,
        w_fc1, wbf1, (INTER * DMODEL) / 4,
        w_fc2, wbf2, (DMODEL * INTER) / 4);
    // 1) LayerNorm -> h (bf16)
    ln_kernel<<<ROWS, 256, 0, stream>>>(hid, ln_w, ln_b, h_bf);
    // 2) in_proj GEMM -> zx (bf16); 256^2 tiles: 41 col x 16 row = 656 blocks
    gemm_q<3><<<41 * 16, 512, 0, stream>>>(
        h_bf, wbi, ROWS, DINPROJ, DMODEL, 16, nullptr, zx, nullptr);
    // 3) chunked SSD scan
    chunk_front<<<BATCH * NHEADS * NC, 256, 0, stream>>>(zx, dtb, A_log, pcum, ybuf, Sbuf);
    chunk_state<<<BATCH * NHEADS * 4, 256, 0, stream>>>(Sbuf, pcum);
    chunk_back<<<BATCH * NHEADS * NC, 256, 0, stream>>>(zx, Sbuf, pcum, Dp, ybuf);
    // 4) gate + RMSNorm -> yf (bf16)
    gate_kernel<<<ROWS, 256, 0, stream>>>(ybuf, zx, nw, yf);
    // 5) fc1 GEMM + gelu -> gelu (bf16); 256^2 tiles: 32 col x 16 row = 512 blocks
    gemm_q<1><<<32 * 16, 512, 0, stream>>>(
        h_bf, wbf1, ROWS, INTER, DMODEL, 16, nullptr, gelu, fc1_b);
    // 6) combined (out_proj + fc2) GEMM over concatenated K = 4096 + 8192 (128x256)
    gemm_p<4><<<8 * 32, 512, 0, stream>>>(
        yf, wbo, ROWS, DMODEL, DINNER + INTER, 32, outF, nullptr, fc2_b, nullptr, hid,
        gelu, wbf2, DINNER);
}